// Round 4
// baseline (827.218 us; speedup 1.0000x reference)
//
#include <hip/hip_runtime.h>
#include <hip/hip_cooperative_groups.h>
#include <cmath>

namespace cg = cooperative_groups;

typedef __attribute__((ext_vector_type(8))) __bf16 v8bf;
typedef __attribute__((ext_vector_type(4))) float  v4f;

#define DEV static __device__ __forceinline__

DEV unsigned short f2bf(float f) {
  unsigned u = __builtin_bit_cast(unsigned, f);
  unsigned r = u + 0x7fffu + ((u >> 16) & 1u);   // RNE
  return (unsigned short)(r >> 16);
}
DEV float bf2f(unsigned short s) {
  return __builtin_bit_cast(float, ((unsigned)s) << 16);
}
DEV v8bf ld8(const unsigned short* p) { return *(const v8bf*)p; }

// async global->LDS, 16 B per lane; LDS dest = wave-uniform base + lane*16
DEV void gl16(const unsigned short* g, unsigned short* l) {
  __builtin_amdgcn_global_load_lds(
      (const __attribute__((address_space(1))) unsigned int*)g,
      (__attribute__((address_space(3))) unsigned int*)l, 16, 0, 0);
}

// ---------------- band-disjoint zero writer (16 rows) ----------------
// Zeros wout rows [rbase, rbase+16) SKIPPING the band [i-127, i].
DEV void zero_rows(float* __restrict__ wout, int rbase, int wave, int lane) {
  int r0 = rbase + wave * 4;
  for (int rr = 0; rr < 4; rr++) {
    int row = r0 + rr;
    int i = row & 2047;
    int lo = i - 127;
    float* rowp = wout + (size_t)row * 2048;
#pragma unroll
    for (int it = 0; it < 8; it++) {
      int col = it * 256 + lane * 4;
      bool full_in = (col >= lo) && (col + 3 <= i);   // fully inside band: skip
      if (full_in) continue;
      bool overlap = (col + 3 >= lo) && (col <= i);   // boundary chunk
      if (!overlap) {
        v4f z = {0.f, 0.f, 0.f, 0.f};
        __builtin_nontemporal_store(z, (v4f*)(rowp + col));
      } else {
#pragma unroll
        for (int e = 0; e < 4; e++) {
          int j = col + e;
          if (j < lo || j > i) rowp[j] = 0.f;
        }
      }
    }
  }
}

// ---------------- prep unit (grid-stride body of old k_prep) ----------------
DEV void prep_unit(int bx, int tid, float* tt,   // tt: 32x33 f32 LDS scratch
                   const float* x, const float* Wq, const float* Wk,
                   const float* Wv, const float* Wo, const float* bq,
                   const float* bk, const float* bv,
                   unsigned short* xb, unsigned short* WT,
                   unsigned short* WoT, float* bqkv) {
  if (bx < 4096) {                               // x fp32 -> bf16, 4 elems/thread
    int i = bx * 256 + tid;
    float4 v = ((const float4*)x)[i];
    unsigned lo = (unsigned)f2bf(v.x) | ((unsigned)f2bf(v.y) << 16);
    unsigned hi = (unsigned)f2bf(v.z) | ((unsigned)f2bf(v.w) << 16);
    ((uint2*)xb)[i] = make_uint2(lo, hi);
  } else if (bx < 8192) {                        // W[k][n] -> WT[n][k] bf16
    int rem = bx - 4096;
    int z = rem >> 10, r2 = rem & 1023;
    const float* src = (z == 0) ? Wq : (z == 1) ? Wk : (z == 2) ? Wv : Wo;
    unsigned short* dst = (z < 3) ? WT + z * 1048576 : WoT;
    int n0 = (r2 & 31) * 32, k0 = (r2 >> 5) * 32;
    int tx = tid & 31, ty = tid >> 5;
    for (int r = ty; r < 32; r += 8)
      tt[r * 33 + tx] = src[(k0 + r) * 1024 + n0 + tx];
    __syncthreads();
    for (int r = ty; r < 32; r += 8)
      dst[(n0 + r) * 1024 + k0 + tx] = f2bf(tt[tx * 33 + r]);
    __syncthreads();                             // protect tt for next unit
  } else {                                       // bias concat
    int i = (bx - 8192) * 256 + tid;
    float v = (i < 1024) ? bq[i] : (i < 2048 ? bk[i - 1024] : bv[i - 2048]);
    bqkv[i] = v;
  }
}

// ---------------- QKV GEMM tile + fused V-transpose ----------------
// 128x128 tile, BK=32, gl16 staging, 4 waves each 64x64.
// Q/K column-tiles (n0<2048) -> QK[4096][2048]; V tiles written transposed
// to Vtg[(b*16+h)*64+d][2048]. As=SM[0..4096), Bs=SM[4096..8192) shorts.
DEV void gemm1_tile(int gid, int tid, unsigned short* SM,
                    const unsigned short* A, const unsigned short* Bt,
                    const float* bias, unsigned short* QK,
                    unsigned short* Vtg) {
  constexpr int K = 1024;
  unsigned short* As = SM;
  unsigned short* Bs = SM + 4096;
  int wave = tid >> 6, lane = tid & 63;
  int n0 = (gid % 24) * 128, m0 = (gid / 24) * 128;
  int wm = (wave >> 1) * 64, wn = (wave & 1) * 64;
  int m = lane & 15, q4 = lane >> 4;
  int arow = tid >> 2, acol = (tid & 3) * 8;
  v4f acc[4][4] = {};
  const unsigned short* ga0 = A + (m0 + arow) * K + acol;
  const unsigned short* ga1 = A + (m0 + 64 + arow) * K + acol;
  const unsigned short* gb0 = Bt + (n0 + arow) * K + acol;
  const unsigned short* gb1 = Bt + (n0 + 64 + arow) * K + acol;
  unsigned short* lA0 = As + wave * 512;
  unsigned short* lA1 = As + 2048 + wave * 512;
  unsigned short* lB0 = Bs + wave * 512;
  unsigned short* lB1 = Bs + 2048 + wave * 512;

  for (int kt = 0; kt < K; kt += 32) {
    gl16(ga0 + kt, lA0);
    gl16(ga1 + kt, lA1);
    gl16(gb0 + kt, lB0);
    gl16(gb1 + kt, lB1);
    __syncthreads();
    v8bf af[4], bfv[4];
#pragma unroll
    for (int mt = 0; mt < 4; mt++) af[mt] = ld8(&As[(wm + mt * 16 + m) * 32 + q4 * 8]);
#pragma unroll
    for (int nt = 0; nt < 4; nt++) bfv[nt] = ld8(&Bs[(wn + nt * 16 + m) * 32 + q4 * 8]);
#pragma unroll
    for (int mt = 0; mt < 4; mt++)
#pragma unroll
      for (int nt = 0; nt < 4; nt++)
        acc[mt][nt] = __builtin_amdgcn_mfma_f32_16x16x32_bf16(af[mt], bfv[nt], acc[mt][nt], 0, 0, 0);
    __syncthreads();
  }
  if (n0 < 2048) {                               // Q,K -> QK[4096][2048]
#pragma unroll
    for (int mt = 0; mt < 4; mt++)
#pragma unroll
      for (int nt = 0; nt < 4; nt++) {
        int col = n0 + wn + nt * 16 + m;
        float bb = bias[col];
#pragma unroll
        for (int r = 0; r < 4; r++) {
          int row = m0 + wm + mt * 16 + q4 * 4 + r;
          QK[row * 2048 + col] = f2bf(acc[mt][nt][r] + bb);
        }
      }
  } else {                                       // V -> Vtg transposed, 8B/lane
    int b = m0 >> 11;
#pragma unroll
    for (int mt = 0; mt < 4; mt++)
#pragma unroll
      for (int nt = 0; nt < 4; nt++) {
        int d = n0 - 2048 + wn + nt * 16 + m;    // [0,1024)
        int h = d >> 6, dd = d & 63;
        float bb = bias[2048 + d];
        int vrow = (b * 16 + h) * 64 + dd;
        int s0 = (m0 + wm + mt * 16 + q4 * 4) & 2047;
        unsigned short u0 = f2bf(acc[mt][nt][0] + bb);
        unsigned short u1 = f2bf(acc[mt][nt][1] + bb);
        unsigned short u2 = f2bf(acc[mt][nt][2] + bb);
        unsigned short u3 = f2bf(acc[mt][nt][3] + bb);
        unsigned lo = (unsigned)u0 | ((unsigned)u1 << 16);
        unsigned hi = (unsigned)u2 | ((unsigned)u3 << 16);
        *(uint2*)&Vtg[(size_t)vrow * 2048 + s0] = make_uint2(lo, hi);
      }
  }
}

// ---------------- sliding-window attention unit (band write direct) ----------
// Vt = SM[0..13312), Ps = SM[13312..24064) shorts.
DEV void attn_unit(int b, int h, int i0, int tid, unsigned short* SM,
                   const unsigned short* QK, const unsigned short* Vtg,
                   unsigned short* Oatt, float* wout) {
  constexpr int VTS = 208;
  constexpr int PSS = 168;
  unsigned short* Vt = SM;
  int wave = tid >> 6, lane = tid & 63;
  unsigned short* Psw = SM + 13312 + wave * (16 * PSS);
  int kbase = i0 - 128;
  const int ld = 2048;
  const unsigned short* Qg = QK + (size_t)b * 2048 * ld + h * 64;
  const unsigned short* Kg = Qg + 1024;

  // stage V from pre-transposed Vtg: 64 d-rows x 192 keys, b128 both sides
  const unsigned short* vsrc = Vtg + (size_t)(b * 16 + h) * 64 * 2048;
  for (int idx = tid; idx < 1536; idx += 256) {
    int row = idx / 24, c16 = idx % 24;
    int gcol = kbase + c16 * 8;
    if (gcol < 0) gcol = 0;                       // clamp; P mask zeroes these keys
    v8bf vv = ld8(vsrc + (size_t)row * 2048 + gcol);
    *(v8bf*)&Vt[row * VTS + c16 * 8] = vv;
  }
  // zero Vt cols [192,208): wave3's PV c=4 chunk reads them
  {
    int row = tid >> 2, c4 = (tid & 3) * 4;
    *(uint2*)&Vt[row * VTS + 192 + c4] = make_uint2(0u, 0u);
  }
  // zero Ps pad cols [144,168)
  for (int c = lane; c < 16 * 24; c += 64)
    Psw[(c / 24) * PSS + 144 + (c % 24)] = 0;
  __syncthreads();

  int qb = i0 + wave * 16;
  int m = lane & 15, q4 = lane >> 4;

  const unsigned short* qrow = Qg + (qb + m) * ld;
  v8bf qa0 = ld8(qrow + q4 * 8);
  v8bf qa1 = ld8(qrow + 32 + q4 * 8);

  v4f sc[9];
#pragma unroll
  for (int n = 0; n < 9; n++) {
    int key = kbase + wave * 16 + n * 16 + m;
    int kg = key < 0 ? 0 : key;
    const unsigned short* krow = Kg + kg * ld;
    v8bf kb0 = ld8(krow + q4 * 8);
    v8bf kb1 = ld8(krow + 32 + q4 * 8);
    v4f z = {0.f, 0.f, 0.f, 0.f};
    z = __builtin_amdgcn_mfma_f32_16x16x32_bf16(qa0, kb0, z, 0, 0, 0);
    z = __builtin_amdgcn_mfma_f32_16x16x32_bf16(qa1, kb1, z, 0, 0, 0);
    sc[n] = z;
  }
  float mx[4] = {-3e38f, -3e38f, -3e38f, -3e38f};
#pragma unroll
  for (int n = 0; n < 9; n++)
#pragma unroll
    for (int r = 0; r < 4; r++) {
      int i = qb + q4 * 4 + r;
      int j = kbase + wave * 16 + n * 16 + m;
      float v = sc[n][r] * 0.125f;
      bool ok = (j >= 0) && (j <= i) && (j > i - 128);
      v = ok ? v : -3e38f;
      sc[n][r] = v;
      mx[r] = fmaxf(mx[r], v);
    }
#pragma unroll
  for (int o = 1; o < 16; o <<= 1)
#pragma unroll
    for (int r = 0; r < 4; r++) mx[r] = fmaxf(mx[r], __shfl_xor(mx[r], o, 64));
  float sum[4] = {0.f, 0.f, 0.f, 0.f};
#pragma unroll
  for (int n = 0; n < 9; n++)
#pragma unroll
    for (int r = 0; r < 4; r++) {
      float p = __expf(sc[n][r] - mx[r]);
      sc[n][r] = p;
      sum[r] += p;
    }
#pragma unroll
  for (int o = 1; o < 16; o <<= 1)
#pragma unroll
    for (int r = 0; r < 4; r++) sum[r] += __shfl_xor(sum[r], o, 64);
  float inv[4];
#pragma unroll
  for (int r = 0; r < 4; r++) inv[r] = 1.0f / sum[r];

#pragma unroll
  for (int n = 0; n < 9; n++)
#pragma unroll
    for (int r = 0; r < 4; r++)
      Psw[(q4 * 4 + r) * PSS + n * 16 + m] = f2bf(sc[n][r] * inv[r]);
  __syncthreads();

  v4f oacc[4] = {};
#pragma unroll
  for (int c = 0; c < 5; c++) {
    v8bf pa = ld8(&Psw[m * PSS + c * 32 + q4 * 8]);
#pragma unroll
    for (int dt = 0; dt < 4; dt++) {
      v8bf vb = ld8(&Vt[(dt * 16 + m) * VTS + wave * 16 + c * 32 + q4 * 8]);
      oacc[dt] = __builtin_amdgcn_mfma_f32_16x16x32_bf16(pa, vb, oacc[dt], 0, 0, 0);
    }
  }
#pragma unroll
  for (int dt = 0; dt < 4; dt++)
#pragma unroll
    for (int r = 0; r < 4; r++)
      Oatt[(b * 2048 + qb + q4 * 4 + r) * 1024 + h * 64 + dt * 16 + m] = f2bf(oacc[dt][r]);

  // band of dense weights, written directly (zero region is band-disjoint).
  for (int R = 0; R < 16; R++) {
    int iq = qb + R;
    float* rowp = wout + (size_t)((b * 16 + h) * 2048 + iq) * 2048;
    int lo = iq - 127;
    int t0 = R + 1 + lane * 2;
    float p0 = bf2f(Psw[R * PSS + t0]);
    float p1 = bf2f(Psw[R * PSS + t0 + 1]);
    int j0 = lo + lane * 2;
    if (j0 >= 0) rowp[j0] = p0;
    if (j0 + 1 >= 0) rowp[j0 + 1] = p1;
  }
}

// ---------------- out-proj GEMM tile ----------------
DEV void tail_tile(int gid, int tid, unsigned short* SM,
                   const unsigned short* Oat, const unsigned short* WoT,
                   const float* bo, float* out) {
  constexpr int K = 1024;
  unsigned short* As = SM;
  unsigned short* Bs = SM + 4096;
  int wave = tid >> 6, lane = tid & 63;
  int n0 = (gid & 7) * 128, m0 = (gid >> 3) * 128;
  int wm = (wave >> 1) * 64, wn = (wave & 1) * 64;
  int m = lane & 15, q4 = lane >> 4;
  int arow = tid >> 2, acol = (tid & 3) * 8;
  v4f acc[4][4] = {};
  const unsigned short* ga0 = Oat + (m0 + arow) * K + acol;
  const unsigned short* ga1 = Oat + (m0 + 64 + arow) * K + acol;
  const unsigned short* gb0 = WoT + (n0 + arow) * K + acol;
  const unsigned short* gb1 = WoT + (n0 + 64 + arow) * K + acol;
  unsigned short* lA0 = As + wave * 512;
  unsigned short* lA1 = As + 2048 + wave * 512;
  unsigned short* lB0 = Bs + wave * 512;
  unsigned short* lB1 = Bs + 2048 + wave * 512;
  for (int kt = 0; kt < K; kt += 32) {
    gl16(ga0 + kt, lA0);
    gl16(ga1 + kt, lA1);
    gl16(gb0 + kt, lB0);
    gl16(gb1 + kt, lB1);
    __syncthreads();
    v8bf af[4], bfv[4];
#pragma unroll
    for (int mt = 0; mt < 4; mt++) af[mt] = ld8(&As[(wm + mt * 16 + m) * 32 + q4 * 8]);
#pragma unroll
    for (int nt = 0; nt < 4; nt++) bfv[nt] = ld8(&Bs[(wn + nt * 16 + m) * 32 + q4 * 8]);
#pragma unroll
    for (int mt = 0; mt < 4; mt++)
#pragma unroll
      for (int nt = 0; nt < 4; nt++)
        acc[mt][nt] = __builtin_amdgcn_mfma_f32_16x16x32_bf16(af[mt], bfv[nt], acc[mt][nt], 0, 0, 0);
    __syncthreads();
  }
#pragma unroll
  for (int mt = 0; mt < 4; mt++)
#pragma unroll
    for (int nt = 0; nt < 4; nt++) {
      int col = n0 + wn + nt * 16 + m;
      float bb = bo[col];
#pragma unroll
      for (int r = 0; r < 4; r++) {
        int row = m0 + wm + mt * 16 + q4 * 4 + r;
        out[row * 1024 + col] = acc[mt][nt][r] + bb;
      }
    }
}

// ---------------- cooperative mega-kernel ----------------
// grid <= 768 blocks x 256 thr, all co-resident (cooperative). Phases separated
// by grid.sync(); within phases an atomic queue interleaves zero-fill chunks
// with compute units so the 503 MB dense write streams WHILE other blocks MFMA
// (write issued in dedicated units -> no gl16-barrier vmcnt coupling).
__global__ __launch_bounds__(256, 2) void k_mega(
    const float* __restrict__ x,  const float* __restrict__ Wq,
    const float* __restrict__ Wk, const float* __restrict__ Wv,
    const float* __restrict__ Wo, const float* __restrict__ bq,
    const float* __restrict__ bk, const float* __restrict__ bv,
    const float* __restrict__ bo,
    unsigned short* __restrict__ xb,  unsigned short* __restrict__ WT,
    unsigned short* __restrict__ WoT, float* __restrict__ bqkv,
    unsigned short* __restrict__ QK,  unsigned short* __restrict__ Vtg,
    unsigned short* __restrict__ Oat, float* __restrict__ out,
    float* __restrict__ wout, unsigned* __restrict__ qctr) {
  cg::grid_group grid = cg::this_grid();
  // LDS union: prep tt (4224B) | gemm As+Bs (16KB) | attn Vt+Ps (48128B)
  __shared__ __attribute__((aligned(16))) unsigned short SM[24064];
  __shared__ unsigned s_u;
  int tid = threadIdx.x, wave = tid >> 6, lane = tid & 63;
  int bid = blockIdx.x, nb = gridDim.x;

  // ---- phase 0: queue reset + prep (grid-stride; 8204 cheap uniform units)
  if (bid == 0 && tid < 3) atomicExch(&qctr[tid], 0u);
  for (int u = bid; u < 8204; u += nb)
    prep_unit(u, tid, (float*)SM, x, Wq, Wk, Wv, Wo, bq, bk, bv, xb, WT, WoT, bqkv);
  grid.sync();

  // ---- phase 1: 2304 units = 768 gemm tiles + 1536 zero chunks (1:2 interleave)
  for (;;) {
    if (tid == 0) s_u = atomicAdd(&qctr[0], 1u);
    __syncthreads();
    unsigned u = s_u;
    __syncthreads();
    if (u >= 2304u) break;
    unsigned r = u % 3u, base = u / 3u;
    if (r == 0) {
      gemm1_tile((int)base, tid, SM, xb, WT, bqkv, QK, Vtg);
    } else {
      int c = (int)(base * 2u + (r - 1u));       // [0,1536): rows [0,49152)
      zero_rows(wout, c * 32, wave, lane);
      zero_rows(wout, c * 32 + 16, wave, lane);
    }
  }
  grid.sync();

  // ---- phase 2: 1536 units = 1024 attn + 512 zero chunks (2:1 interleave)
  for (;;) {
    if (tid == 0) s_u = atomicAdd(&qctr[1], 1u);
    __syncthreads();
    unsigned u = s_u;
    __syncthreads();
    if (u >= 1536u) break;
    unsigned r = u % 3u, base = u / 3u;
    if (r < 2) {
      int a = (int)(base * 2u + r);              // [0,1024)
      int i0 = (a & 31) * 64, h = (a >> 5) & 15, b = a >> 9;
      attn_unit(b, h, i0, tid, SM, QK, Vtg, Oat, wout);
    } else {
      int c = 1536 + (int)base;                  // [1536,2048): rows [49152,65536)
      zero_rows(wout, c * 32, wave, lane);
      zero_rows(wout, c * 32 + 16, wave, lane);
    }
  }
  grid.sync();

  // ---- phase 3: 256 out-proj tiles
  for (;;) {
    if (tid == 0) s_u = atomicAdd(&qctr[2], 1u);
    __syncthreads();
    unsigned u = s_u;
    __syncthreads();
    if (u >= 256u) break;
    tail_tile((int)u, tid, SM, Oat, WoT, bo, out);
  }
}

// ---------------- host launch ----------------
extern "C" void kernel_launch(void* const* d_in, const int* in_sizes, int n_in,
                              void* d_out, int out_size, void* d_ws, size_t ws_size,
                              hipStream_t stream) {
  (void)in_sizes; (void)n_in; (void)out_size; (void)ws_size;
  const float* x  = (const float*)d_in[0];
  const float* Wq = (const float*)d_in[1];
  const float* bq = (const float*)d_in[2];
  const float* Wk = (const float*)d_in[3];
  const float* bk = (const float*)d_in[4];
  const float* Wv = (const float*)d_in[5];
  const float* bv = (const float*)d_in[6];
  const float* Wo = (const float*)d_in[7];
  const float* bo = (const float*)d_in[8];

  char* ws = (char*)d_ws;
  unsigned short* xb   = (unsigned short*)(ws);                  //  8,388,608 B
  unsigned short* WT   = (unsigned short*)(ws + 8388608);        //  6,291,456 B  [3072][1024]
  unsigned short* WoT  = (unsigned short*)(ws + 14680064);       //  2,097,152 B  [1024][1024]
  float*          bqkv = (float*)(ws + 16777216);                //     12,288 B
  unsigned short* QK   = (unsigned short*)(ws + 16789504);       // 16,777,216 B  [4096][2048]
  unsigned short* Oat  = (unsigned short*)(ws + 33566720);       //  8,388,608 B  [4096][1024]
  unsigned short* Vtg  = (unsigned short*)(ws + 41955328);       //  8,388,608 B  [2048][2048]
  unsigned*       qctr = (unsigned*)(ws + 50343936);             //         16 B

  float* out  = (float*)d_out;          // [2,2048,1024]
  float* wout = out + 4194304;          // [2,16,2048,2048]

  static int occ = 0;                   // queried once; host-side only, capture-safe
  if (occ == 0) {
    int tmp = 0;
    if (hipOccupancyMaxActiveBlocksPerMultiprocessor(&tmp, k_mega, 256, 0) != hipSuccess || tmp < 1)
      tmp = 1;
    occ = tmp;
  }
  int nb = occ * 256;
  if (nb > 768) nb = 768;
  if (nb < 256) nb = 256;

  void* args[] = {(void*)&x,  (void*)&Wq, (void*)&Wk, (void*)&Wv, (void*)&Wo,
                  (void*)&bq, (void*)&bk, (void*)&bv, (void*)&bo,
                  (void*)&xb, (void*)&WT, (void*)&WoT, (void*)&bqkv,
                  (void*)&QK, (void*)&Vtg, (void*)&Oat, (void*)&out,
                  (void*)&wout, (void*)&qctr};
  hipLaunchCooperativeKernel((const void*)k_mega, dim3(nb), dim3(256), args, 0, stream);
}

// Round 5
// 678.293 us; speedup vs baseline: 1.2196x; 1.2196x over previous
//
#include <hip/hip_runtime.h>
#include <cmath>

typedef __attribute__((ext_vector_type(8))) __bf16 v8bf;
typedef __attribute__((ext_vector_type(4))) float  v4f;

#define DEV static __device__ __forceinline__

DEV unsigned short f2bf(float f) {
  unsigned u = __builtin_bit_cast(unsigned, f);
  unsigned r = u + 0x7fffu + ((u >> 16) & 1u);   // RNE
  return (unsigned short)(r >> 16);
}
DEV float bf2f(unsigned short s) {
  return __builtin_bit_cast(float, ((unsigned)s) << 16);
}
DEV v8bf ld8(const unsigned short* p) { return *(const v8bf*)p; }

// async global->LDS, 16 B per lane; LDS dest = wave-uniform base + lane*16
DEV void gl16(const unsigned short* g, unsigned short* l) {
  __builtin_amdgcn_global_load_lds(
      (const __attribute__((address_space(1))) unsigned int*)g,
      (__attribute__((address_space(3))) unsigned int*)l, 16, 0, 0);
}

// ---------------- fused prep: cvt_x | weight transpose | bias pack ----------------
__global__ __launch_bounds__(256) void k_prep(const float* __restrict__ x,
                                              const float* __restrict__ Wq,
                                              const float* __restrict__ Wk,
                                              const float* __restrict__ Wv,
                                              const float* __restrict__ Wo,
                                              const float* __restrict__ bq,
                                              const float* __restrict__ bk,
                                              const float* __restrict__ bv,
                                              unsigned short* __restrict__ xb,
                                              unsigned short* __restrict__ WT,
                                              unsigned short* __restrict__ WoT,
                                              float* __restrict__ bqkv) {
  __shared__ float t[32][33];
  int bx = blockIdx.x, tid = threadIdx.x;
  if (bx < 4096) {                               // x fp32 -> bf16, 4 elems/thread
    int i = bx * 256 + tid;
    float4 v = ((const float4*)x)[i];
    unsigned lo = (unsigned)f2bf(v.x) | ((unsigned)f2bf(v.y) << 16);
    unsigned hi = (unsigned)f2bf(v.z) | ((unsigned)f2bf(v.w) << 16);
    ((uint2*)xb)[i] = make_uint2(lo, hi);
  } else if (bx < 8192) {                        // W[k][n] -> WT[n][k] bf16
    int rem = bx - 4096;
    int z = rem >> 10, r2 = rem & 1023;
    const float* src = (z == 0) ? Wq : (z == 1) ? Wk : (z == 2) ? Wv : Wo;
    unsigned short* dst = (z < 3) ? WT + z * 1048576 : WoT;
    int n0 = (r2 & 31) * 32, k0 = (r2 >> 5) * 32;
    int tx = tid & 31, ty = tid >> 5;
    for (int r = ty; r < 32; r += 8)
      t[r][tx] = src[(k0 + r) * 1024 + n0 + tx];
    __syncthreads();
    for (int r = ty; r < 32; r += 8)
      dst[(n0 + r) * 1024 + k0 + tx] = f2bf(t[tx][r]);
  } else {                                       // bias concat
    int i = (bx - 8192) * 256 + tid;
    float v = (i < 1024) ? bq[i] : (i < 2048 ? bk[i - 1024] : bv[i - 2048]);
    bqkv[i] = v;
  }
}

// ---------------- QKV GEMM + fused V-transpose (pure) ----------------
// 128x128 tile, BK=32, gl16 staging, 4 waves each 64x64. grid 768.
// Q/K column-tiles (n0<2048) -> QK[4096][2048]; V tiles (n0>=2048) written
// TRANSPOSED straight to Vtg[(b*16+h)*64+d][2048].
__global__ __launch_bounds__(256) void k_gemm1(const unsigned short* __restrict__ A,
                                               const unsigned short* __restrict__ Bt,
                                               const float* __restrict__ bias,
                                               unsigned short* __restrict__ QK,
                                               unsigned short* __restrict__ Vtg) {
  constexpr int K = 1024;
  __shared__ __attribute__((aligned(16))) unsigned short As[128 * 32];
  __shared__ __attribute__((aligned(16))) unsigned short Bs[128 * 32];
  int tid = threadIdx.x;
  int wave = tid >> 6, lane = tid & 63;
  int gid = blockIdx.x;
  int n0 = (gid % 24) * 128, m0 = (gid / 24) * 128;
  int wm = (wave >> 1) * 64, wn = (wave & 1) * 64;
  int m = lane & 15, q4 = lane >> 4;
  int arow = tid >> 2, acol = (tid & 3) * 8;
  v4f acc[4][4] = {};
  const unsigned short* ga0 = A + (m0 + arow) * K + acol;
  const unsigned short* ga1 = A + (m0 + 64 + arow) * K + acol;
  const unsigned short* gb0 = Bt + (n0 + arow) * K + acol;
  const unsigned short* gb1 = Bt + (n0 + 64 + arow) * K + acol;
  unsigned short* lA0 = As + wave * 512;
  unsigned short* lA1 = As + 2048 + wave * 512;
  unsigned short* lB0 = Bs + wave * 512;
  unsigned short* lB1 = Bs + 2048 + wave * 512;

  for (int kt = 0; kt < K; kt += 32) {
    gl16(ga0 + kt, lA0);
    gl16(ga1 + kt, lA1);
    gl16(gb0 + kt, lB0);
    gl16(gb1 + kt, lB1);
    __syncthreads();
    v8bf af[4], bfv[4];
#pragma unroll
    for (int mt = 0; mt < 4; mt++) af[mt] = ld8(&As[(wm + mt * 16 + m) * 32 + q4 * 8]);
#pragma unroll
    for (int nt = 0; nt < 4; nt++) bfv[nt] = ld8(&Bs[(wn + nt * 16 + m) * 32 + q4 * 8]);
#pragma unroll
    for (int mt = 0; mt < 4; mt++)
#pragma unroll
      for (int nt = 0; nt < 4; nt++)
        acc[mt][nt] = __builtin_amdgcn_mfma_f32_16x16x32_bf16(af[mt], bfv[nt], acc[mt][nt], 0, 0, 0);
    __syncthreads();
  }
  if (n0 < 2048) {                               // Q,K -> QK[4096][2048]
#pragma unroll
    for (int mt = 0; mt < 4; mt++)
#pragma unroll
      for (int nt = 0; nt < 4; nt++) {
        int col = n0 + wn + nt * 16 + m;
        float bb = bias[col];
#pragma unroll
        for (int r = 0; r < 4; r++) {
          int row = m0 + wm + mt * 16 + q4 * 4 + r;
          QK[row * 2048 + col] = f2bf(acc[mt][nt][r] + bb);
        }
      }
  } else {                                       // V -> Vtg transposed, 8B/lane
    int b = m0 >> 11;
#pragma unroll
    for (int mt = 0; mt < 4; mt++)
#pragma unroll
      for (int nt = 0; nt < 4; nt++) {
        int d = n0 - 2048 + wn + nt * 16 + m;    // [0,1024)
        int h = d >> 6, dd = d & 63;
        float bb = bias[2048 + d];
        int vrow = (b * 16 + h) * 64 + dd;
        int s0 = (m0 + wm + mt * 16 + q4 * 4) & 2047;
        unsigned short u0 = f2bf(acc[mt][nt][0] + bb);
        unsigned short u1 = f2bf(acc[mt][nt][1] + bb);
        unsigned short u2 = f2bf(acc[mt][nt][2] + bb);
        unsigned short u3 = f2bf(acc[mt][nt][3] + bb);
        unsigned lo = (unsigned)u0 | ((unsigned)u1 << 16);
        unsigned hi = (unsigned)u2 | ((unsigned)u3 << 16);
        *(uint2*)&Vtg[(size_t)vrow * 2048 + s0] = make_uint2(lo, hi);
      }
  }
}

// ---------------- sliding-window attention (band only; wout pre-zeroed) --------
// grid dim3(32,16,2): one block = (b, h, 64 queries), 4 waves x 16 q.
// Writes Oatt bf16 + the wout band directly (wout zeros come from the
// hipMemsetAsync issued at the head of the stream; band overwrites it here).
__global__ __launch_bounds__(256) void k_attn(const unsigned short* __restrict__ QK,
                                              const unsigned short* __restrict__ Vtg,
                                              unsigned short* __restrict__ Oatt,
                                              float* __restrict__ wout) {
  constexpr int VTS = 208;
  constexpr int PSS = 168;
  __shared__ __attribute__((aligned(16))) unsigned short Vt[64 * VTS];
  __shared__ __attribute__((aligned(16))) unsigned short Ps[4][16 * PSS];
  int tid = threadIdx.x, wave = tid >> 6, lane = tid & 63;
  int b = blockIdx.z, h = blockIdx.y, i0 = blockIdx.x * 64;
  int kbase = i0 - 128;
  const int ld = 2048;
  const unsigned short* Qg = QK + (size_t)b * 2048 * ld + h * 64;
  const unsigned short* Kg = Qg + 1024;

  // stage V from pre-transposed Vtg: 64 d-rows x 192 keys, b128 both sides
  const unsigned short* vsrc = Vtg + (size_t)(b * 16 + h) * 64 * 2048;
  for (int idx = tid; idx < 1536; idx += 256) {
    int row = idx / 24, c16 = idx % 24;
    int gcol = kbase + c16 * 8;
    if (gcol < 0) gcol = 0;                       // clamp; P mask zeroes these keys
    v8bf vv = ld8(vsrc + (size_t)row * 2048 + gcol);
    *(v8bf*)&Vt[row * VTS + c16 * 8] = vv;
  }
  // zero Vt cols [192,208): wave3's PV c=4 chunk reads them
  {
    int row = tid >> 2, c4 = (tid & 3) * 4;
    *(uint2*)&Vt[row * VTS + 192 + c4] = make_uint2(0u, 0u);
  }
  // zero Ps pad cols [144,168)
  for (int c = lane; c < 16 * 24; c += 64)
    Ps[wave][(c / 24) * PSS + 144 + (c % 24)] = 0;
  __syncthreads();

  int qb = i0 + wave * 16;
  int m = lane & 15, q4 = lane >> 4;

  const unsigned short* qrow = Qg + (qb + m) * ld;
  v8bf qa0 = ld8(qrow + q4 * 8);
  v8bf qa1 = ld8(qrow + 32 + q4 * 8);

  v4f sc[9];
#pragma unroll
  for (int n = 0; n < 9; n++) {
    int key = kbase + wave * 16 + n * 16 + m;
    int kg = key < 0 ? 0 : key;
    const unsigned short* krow = Kg + kg * ld;
    v8bf kb0 = ld8(krow + q4 * 8);
    v8bf kb1 = ld8(krow + 32 + q4 * 8);
    v4f z = {0.f, 0.f, 0.f, 0.f};
    z = __builtin_amdgcn_mfma_f32_16x16x32_bf16(qa0, kb0, z, 0, 0, 0);
    z = __builtin_amdgcn_mfma_f32_16x16x32_bf16(qa1, kb1, z, 0, 0, 0);
    sc[n] = z;
  }
  float mx[4] = {-3e38f, -3e38f, -3e38f, -3e38f};
#pragma unroll
  for (int n = 0; n < 9; n++)
#pragma unroll
    for (int r = 0; r < 4; r++) {
      int i = qb + q4 * 4 + r;
      int j = kbase + wave * 16 + n * 16 + m;
      float v = sc[n][r] * 0.125f;
      bool ok = (j >= 0) && (j <= i) && (j > i - 128);
      v = ok ? v : -3e38f;
      sc[n][r] = v;
      mx[r] = fmaxf(mx[r], v);
    }
#pragma unroll
  for (int o = 1; o < 16; o <<= 1)
#pragma unroll
    for (int r = 0; r < 4; r++) mx[r] = fmaxf(mx[r], __shfl_xor(mx[r], o, 64));
  float sum[4] = {0.f, 0.f, 0.f, 0.f};
#pragma unroll
  for (int n = 0; n < 9; n++)
#pragma unroll
    for (int r = 0; r < 4; r++) {
      float p = __expf(sc[n][r] - mx[r]);
      sc[n][r] = p;
      sum[r] += p;
    }
#pragma unroll
  for (int o = 1; o < 16; o <<= 1)
#pragma unroll
    for (int r = 0; r < 4; r++) sum[r] += __shfl_xor(sum[r], o, 64);
  float inv[4];
#pragma unroll
  for (int r = 0; r < 4; r++) inv[r] = 1.0f / sum[r];

#pragma unroll
  for (int n = 0; n < 9; n++)
#pragma unroll
    for (int r = 0; r < 4; r++)
      Ps[wave][(q4 * 4 + r) * PSS + n * 16 + m] = f2bf(sc[n][r] * inv[r]);
  __syncthreads();

  v4f oacc[4] = {};
#pragma unroll
  for (int c = 0; c < 5; c++) {
    v8bf pa = ld8(&Ps[wave][m * PSS + c * 32 + q4 * 8]);
#pragma unroll
    for (int dt = 0; dt < 4; dt++) {
      v8bf vb = ld8(&Vt[(dt * 16 + m) * VTS + wave * 16 + c * 32 + q4 * 8]);
      oacc[dt] = __builtin_amdgcn_mfma_f32_16x16x32_bf16(pa, vb, oacc[dt], 0, 0, 0);
    }
  }
#pragma unroll
  for (int dt = 0; dt < 4; dt++)
#pragma unroll
    for (int r = 0; r < 4; r++)
      Oatt[(b * 2048 + qb + q4 * 4 + r) * 1024 + h * 64 + dt * 16 + m] = f2bf(oacc[dt][r]);

  // band of dense weights, written directly over the memset zeros.
  for (int R = 0; R < 16; R++) {
    int iq = qb + R;
    float* rowp = wout + (size_t)((b * 16 + h) * 2048 + iq) * 2048;
    int lo = iq - 127;
    int t0 = R + 1 + lane * 2;
    float p0 = bf2f(Ps[wave][R * PSS + t0]);
    float p1 = bf2f(Ps[wave][R * PSS + t0 + 1]);
    int j0 = lo + lane * 2;
    if (j0 >= 0) rowp[j0] = p0;
    if (j0 + 1 >= 0) rowp[j0 + 1] = p1;
  }
}

// ---------------- out-proj GEMM: out[4096][1024] = Oat x WoT^T + bo ----------
__global__ __launch_bounds__(256) void k_tail(const unsigned short* __restrict__ Oat,
                                              const unsigned short* __restrict__ WoT,
                                              const float* __restrict__ bo,
                                              float* __restrict__ out) {
  __shared__ __attribute__((aligned(16))) unsigned short As[128 * 32];
  __shared__ __attribute__((aligned(16))) unsigned short Bs[128 * 32];
  int tid = threadIdx.x, wave = tid >> 6, lane = tid & 63;
  int bx = blockIdx.x;
  constexpr int K = 1024;
  int n0 = (bx & 7) * 128, m0 = (bx >> 3) * 128;
  int wm = (wave >> 1) * 64, wn = (wave & 1) * 64;
  int m = lane & 15, q4 = lane >> 4;
  int arow = tid >> 2, acol = (tid & 3) * 8;
  v4f acc[4][4] = {};
  const unsigned short* ga0 = Oat + (m0 + arow) * K + acol;
  const unsigned short* ga1 = Oat + (m0 + 64 + arow) * K + acol;
  const unsigned short* gb0 = WoT + (n0 + arow) * K + acol;
  const unsigned short* gb1 = WoT + (n0 + 64 + arow) * K + acol;
  unsigned short* lA0 = As + wave * 512;
  unsigned short* lA1 = As + 2048 + wave * 512;
  unsigned short* lB0 = Bs + wave * 512;
  unsigned short* lB1 = Bs + 2048 + wave * 512;
  for (int kt = 0; kt < K; kt += 32) {
    gl16(ga0 + kt, lA0);
    gl16(ga1 + kt, lA1);
    gl16(gb0 + kt, lB0);
    gl16(gb1 + kt, lB1);
    __syncthreads();
    v8bf af[4], bfv[4];
#pragma unroll
    for (int mt = 0; mt < 4; mt++) af[mt] = ld8(&As[(wm + mt * 16 + m) * 32 + q4 * 8]);
#pragma unroll
    for (int nt = 0; nt < 4; nt++) bfv[nt] = ld8(&Bs[(wn + nt * 16 + m) * 32 + q4 * 8]);
#pragma unroll
    for (int mt = 0; mt < 4; mt++)
#pragma unroll
      for (int nt = 0; nt < 4; nt++)
        acc[mt][nt] = __builtin_amdgcn_mfma_f32_16x16x32_bf16(af[mt], bfv[nt], acc[mt][nt], 0, 0, 0);
    __syncthreads();
  }
#pragma unroll
  for (int mt = 0; mt < 4; mt++)
#pragma unroll
    for (int nt = 0; nt < 4; nt++) {
      int col = n0 + wn + nt * 16 + m;
      float bb = bo[col];
#pragma unroll
      for (int r = 0; r < 4; r++) {
        int row = m0 + wm + mt * 16 + q4 * 4 + r;
        out[row * 1024 + col] = acc[mt][nt][r] + bb;
      }
    }
}

// ---------------- host launch ----------------
extern "C" void kernel_launch(void* const* d_in, const int* in_sizes, int n_in,
                              void* d_out, int out_size, void* d_ws, size_t ws_size,
                              hipStream_t stream) {
  (void)in_sizes; (void)n_in; (void)out_size; (void)ws_size;
  const float* x  = (const float*)d_in[0];
  const float* Wq = (const float*)d_in[1];
  const float* bq = (const float*)d_in[2];
  const float* Wk = (const float*)d_in[3];
  const float* bk = (const float*)d_in[4];
  const float* Wv = (const float*)d_in[5];
  const float* bv = (const float*)d_in[6];
  const float* Wo = (const float*)d_in[7];
  const float* bo = (const float*)d_in[8];

  char* ws = (char*)d_ws;
  unsigned short* xb   = (unsigned short*)(ws);                  //  8,388,608 B
  unsigned short* WT   = (unsigned short*)(ws + 8388608);        //  6,291,456 B  [3072][1024]
  unsigned short* WoT  = (unsigned short*)(ws + 14680064);       //  2,097,152 B  [1024][1024]
  float*          bqkv = (float*)(ws + 16777216);                //     12,288 B
  unsigned short* QK   = (unsigned short*)(ws + 16789504);       // 16,777,216 B  [4096][2048]
  unsigned short* Oat  = (unsigned short*)(ws + 33566720);       //  8,388,608 B  [4096][1024]
  unsigned short* Vtg  = (unsigned short*)(ws + 41955328);       //  8,388,608 B  [2048][2048]

  float* out  = (float*)d_out;          // [2,2048,1024]
  float* wout = out + 4194304;          // [2,16,2048,2048]

  // max-rate zero fill of the dense attn-weights output (band overwritten by
  // k_attn later in stream order). Capture-safe: memset nodes are supported.
  hipMemsetAsync(wout, 0, 536870912ull, stream);

  k_prep<<<8204, 256, 0, stream>>>(x, Wq, Wk, Wv, Wo, bq, bk, bv, xb, WT, WoT, bqkv);
  k_gemm1<<<768, 256, 0, stream>>>(xb, WT, bqkv, QK, Vtg);          // pure QKV gemm + Vtg
  k_attn<<<dim3(32, 16, 2), 256, 0, stream>>>(QK, Vtg, Oat, wout);  // attn + band write
  k_tail<<<256, 256, 0, stream>>>(Oat, WoT, bo, out);               // pure out-proj gemm
}

// Round 6
// 657.792 us; speedup vs baseline: 1.2576x; 1.0312x over previous
//
#include <hip/hip_runtime.h>
#include <cmath>

typedef __attribute__((ext_vector_type(8))) __bf16 v8bf;
typedef __attribute__((ext_vector_type(4))) float  v4f;

#define DEV static __device__ __forceinline__

DEV unsigned short f2bf(float f) {
  unsigned u = __builtin_bit_cast(unsigned, f);
  unsigned r = u + 0x7fffu + ((u >> 16) & 1u);   // RNE
  return (unsigned short)(r >> 16);
}
DEV float bf2f(unsigned short s) {
  return __builtin_bit_cast(float, ((unsigned)s) << 16);
}
DEV v8bf ld8(const unsigned short* p) { return *(const v8bf*)p; }

// async global->LDS, 16 B per lane; LDS dest = wave-uniform base + lane*16
DEV void gl16(const unsigned short* g, unsigned short* l) {
  __builtin_amdgcn_global_load_lds(
      (const __attribute__((address_space(1))) unsigned int*)g,
      (__attribute__((address_space(3))) unsigned int*)l, 16, 0, 0);
}

// ---------------- band-disjoint zero writer (16 rows) ----------------
// Zeros wout rows [rbase, rbase+16) SKIPPING the band [i-127, i]; the band is
// written by k_attn earlier in stream order, so skipping keeps it intact.
DEV void zero_rows(float* __restrict__ wout, int rbase, int wave, int lane) {
  int r0 = rbase + wave * 4;
  for (int rr = 0; rr < 4; rr++) {
    int row = r0 + rr;
    int i = row & 2047;
    int lo = i - 127;
    float* rowp = wout + (size_t)row * 2048;
#pragma unroll
    for (int it = 0; it < 8; it++) {
      int col = it * 256 + lane * 4;
      bool overlap = (col + 3 >= lo) && (col <= i);   // chunk touches band
      if (!overlap) {
        v4f z = {0.f, 0.f, 0.f, 0.f};
        __builtin_nontemporal_store(z, (v4f*)(rowp + col));
      } else {
#pragma unroll
        for (int e = 0; e < 4; e++) {
          int j = col + e;
          if (j < lo || j > i) rowp[j] = 0.f;
        }
      }
    }
  }
}

// ---------------- fused prep: cvt_x | weight transpose | bias pack ----------------
__global__ __launch_bounds__(256) void k_prep(const float* __restrict__ x,
                                              const float* __restrict__ Wq,
                                              const float* __restrict__ Wk,
                                              const float* __restrict__ Wv,
                                              const float* __restrict__ Wo,
                                              const float* __restrict__ bq,
                                              const float* __restrict__ bk,
                                              const float* __restrict__ bv,
                                              unsigned short* __restrict__ xb,
                                              unsigned short* __restrict__ WT,
                                              unsigned short* __restrict__ WoT,
                                              float* __restrict__ bqkv) {
  __shared__ float t[32][33];
  int bx = blockIdx.x, tid = threadIdx.x;
  if (bx < 4096) {                               // x fp32 -> bf16, 4 elems/thread
    int i = bx * 256 + tid;
    float4 v = ((const float4*)x)[i];
    unsigned lo = (unsigned)f2bf(v.x) | ((unsigned)f2bf(v.y) << 16);
    unsigned hi = (unsigned)f2bf(v.z) | ((unsigned)f2bf(v.w) << 16);
    ((uint2*)xb)[i] = make_uint2(lo, hi);
  } else if (bx < 8192) {                        // W[k][n] -> WT[n][k] bf16
    int rem = bx - 4096;
    int z = rem >> 10, r2 = rem & 1023;
    const float* src = (z == 0) ? Wq : (z == 1) ? Wk : (z == 2) ? Wv : Wo;
    unsigned short* dst = (z < 3) ? WT + z * 1048576 : WoT;
    int n0 = (r2 & 31) * 32, k0 = (r2 >> 5) * 32;
    int tx = tid & 31, ty = tid >> 5;
    for (int r = ty; r < 32; r += 8)
      t[r][tx] = src[(k0 + r) * 1024 + n0 + tx];
    __syncthreads();
    for (int r = ty; r < 32; r += 8)
      dst[(n0 + r) * 1024 + k0 + tx] = f2bf(t[tx][r]);
  } else {                                       // bias concat
    int i = (bx - 8192) * 256 + tid;
    float v = (i < 1024) ? bq[i] : (i < 2048 ? bk[i - 1024] : bv[i - 2048]);
    bqkv[i] = v;
  }
}

// ---------------- QKV GEMM + fused V-transpose (pure) ----------------
// 128x128 tile, BK=32, gl16 staging, 4 waves each 64x64. grid 768.
// Q/K column-tiles (n0<2048) -> QK[4096][2048]; V tiles (n0>=2048) written
// TRANSPOSED straight to Vtg[(b*16+h)*64+d][2048].
__global__ __launch_bounds__(256) void k_gemm1(const unsigned short* __restrict__ A,
                                               const unsigned short* __restrict__ Bt,
                                               const float* __restrict__ bias,
                                               unsigned short* __restrict__ QK,
                                               unsigned short* __restrict__ Vtg) {
  constexpr int K = 1024;
  __shared__ __attribute__((aligned(16))) unsigned short As[128 * 32];
  __shared__ __attribute__((aligned(16))) unsigned short Bs[128 * 32];
  int tid = threadIdx.x;
  int wave = tid >> 6, lane = tid & 63;
  int gid = blockIdx.x;
  int n0 = (gid % 24) * 128, m0 = (gid / 24) * 128;
  int wm = (wave >> 1) * 64, wn = (wave & 1) * 64;
  int m = lane & 15, q4 = lane >> 4;
  int arow = tid >> 2, acol = (tid & 3) * 8;
  v4f acc[4][4] = {};
  const unsigned short* ga0 = A + (m0 + arow) * K + acol;
  const unsigned short* ga1 = A + (m0 + 64 + arow) * K + acol;
  const unsigned short* gb0 = Bt + (n0 + arow) * K + acol;
  const unsigned short* gb1 = Bt + (n0 + 64 + arow) * K + acol;
  unsigned short* lA0 = As + wave * 512;
  unsigned short* lA1 = As + 2048 + wave * 512;
  unsigned short* lB0 = Bs + wave * 512;
  unsigned short* lB1 = Bs + 2048 + wave * 512;

  for (int kt = 0; kt < K; kt += 32) {
    gl16(ga0 + kt, lA0);
    gl16(ga1 + kt, lA1);
    gl16(gb0 + kt, lB0);
    gl16(gb1 + kt, lB1);
    __syncthreads();
    v8bf af[4], bfv[4];
#pragma unroll
    for (int mt = 0; mt < 4; mt++) af[mt] = ld8(&As[(wm + mt * 16 + m) * 32 + q4 * 8]);
#pragma unroll
    for (int nt = 0; nt < 4; nt++) bfv[nt] = ld8(&Bs[(wn + nt * 16 + m) * 32 + q4 * 8]);
#pragma unroll
    for (int mt = 0; mt < 4; mt++)
#pragma unroll
      for (int nt = 0; nt < 4; nt++)
        acc[mt][nt] = __builtin_amdgcn_mfma_f32_16x16x32_bf16(af[mt], bfv[nt], acc[mt][nt], 0, 0, 0);
    __syncthreads();
  }
  if (n0 < 2048) {                               // Q,K -> QK[4096][2048]
#pragma unroll
    for (int mt = 0; mt < 4; mt++)
#pragma unroll
      for (int nt = 0; nt < 4; nt++) {
        int col = n0 + wn + nt * 16 + m;
        float bb = bias[col];
#pragma unroll
        for (int r = 0; r < 4; r++) {
          int row = m0 + wm + mt * 16 + q4 * 4 + r;
          QK[row * 2048 + col] = f2bf(acc[mt][nt][r] + bb);
        }
      }
  } else {                                       // V -> Vtg transposed, 8B/lane
    int b = m0 >> 11;
#pragma unroll
    for (int mt = 0; mt < 4; mt++)
#pragma unroll
      for (int nt = 0; nt < 4; nt++) {
        int d = n0 - 2048 + wn + nt * 16 + m;    // [0,1024)
        int h = d >> 6, dd = d & 63;
        float bb = bias[2048 + d];
        int vrow = (b * 16 + h) * 64 + dd;
        int s0 = (m0 + wm + mt * 16 + q4 * 4) & 2047;
        unsigned short u0 = f2bf(acc[mt][nt][0] + bb);
        unsigned short u1 = f2bf(acc[mt][nt][1] + bb);
        unsigned short u2 = f2bf(acc[mt][nt][2] + bb);
        unsigned short u3 = f2bf(acc[mt][nt][3] + bb);
        unsigned lo = (unsigned)u0 | ((unsigned)u1 << 16);
        unsigned hi = (unsigned)u2 | ((unsigned)u3 << 16);
        *(uint2*)&Vtg[(size_t)vrow * 2048 + s0] = make_uint2(lo, hi);
      }
  }
}

// ---------------- sliding-window attention (band write direct) ----------------
// grid dim3(32,16,2): one block = (b, h, 64 queries), 4 waves x 16 q.
// Writes Oatt bf16 + the wout band; zeros are filled by k_tail's writer
// blocks (band-skip) afterwards in stream order.
__global__ __launch_bounds__(256) void k_attn(const unsigned short* __restrict__ QK,
                                              const unsigned short* __restrict__ Vtg,
                                              unsigned short* __restrict__ Oatt,
                                              float* __restrict__ wout) {
  constexpr int VTS = 208;
  constexpr int PSS = 168;
  __shared__ __attribute__((aligned(16))) unsigned short Vt[64 * VTS];
  __shared__ __attribute__((aligned(16))) unsigned short Ps[4][16 * PSS];
  int tid = threadIdx.x, wave = tid >> 6, lane = tid & 63;
  int b = blockIdx.z, h = blockIdx.y, i0 = blockIdx.x * 64;
  int kbase = i0 - 128;
  const int ld = 2048;
  const unsigned short* Qg = QK + (size_t)b * 2048 * ld + h * 64;
  const unsigned short* Kg = Qg + 1024;

  // stage V from pre-transposed Vtg: 64 d-rows x 192 keys, b128 both sides
  const unsigned short* vsrc = Vtg + (size_t)(b * 16 + h) * 64 * 2048;
  for (int idx = tid; idx < 1536; idx += 256) {
    int row = idx / 24, c16 = idx % 24;
    int gcol = kbase + c16 * 8;
    if (gcol < 0) gcol = 0;                       // clamp; P mask zeroes these keys
    v8bf vv = ld8(vsrc + (size_t)row * 2048 + gcol);
    *(v8bf*)&Vt[row * VTS + c16 * 8] = vv;
  }
  // zero Vt cols [192,208): wave3's PV c=4 chunk reads them
  {
    int row = tid >> 2, c4 = (tid & 3) * 4;
    *(uint2*)&Vt[row * VTS + 192 + c4] = make_uint2(0u, 0u);
  }
  // zero Ps pad cols [144,168)
  for (int c = lane; c < 16 * 24; c += 64)
    Ps[wave][(c / 24) * PSS + 144 + (c % 24)] = 0;
  __syncthreads();

  int qb = i0 + wave * 16;
  int m = lane & 15, q4 = lane >> 4;

  const unsigned short* qrow = Qg + (qb + m) * ld;
  v8bf qa0 = ld8(qrow + q4 * 8);
  v8bf qa1 = ld8(qrow + 32 + q4 * 8);

  v4f sc[9];
#pragma unroll
  for (int n = 0; n < 9; n++) {
    int key = kbase + wave * 16 + n * 16 + m;
    int kg = key < 0 ? 0 : key;
    const unsigned short* krow = Kg + kg * ld;
    v8bf kb0 = ld8(krow + q4 * 8);
    v8bf kb1 = ld8(krow + 32 + q4 * 8);
    v4f z = {0.f, 0.f, 0.f, 0.f};
    z = __builtin_amdgcn_mfma_f32_16x16x32_bf16(qa0, kb0, z, 0, 0, 0);
    z = __builtin_amdgcn_mfma_f32_16x16x32_bf16(qa1, kb1, z, 0, 0, 0);
    sc[n] = z;
  }
  float mx[4] = {-3e38f, -3e38f, -3e38f, -3e38f};
#pragma unroll
  for (int n = 0; n < 9; n++)
#pragma unroll
    for (int r = 0; r < 4; r++) {
      int i = qb + q4 * 4 + r;
      int j = kbase + wave * 16 + n * 16 + m;
      float v = sc[n][r] * 0.125f;
      bool ok = (j >= 0) && (j <= i) && (j > i - 128);
      v = ok ? v : -3e38f;
      sc[n][r] = v;
      mx[r] = fmaxf(mx[r], v);
    }
#pragma unroll
  for (int o = 1; o < 16; o <<= 1)
#pragma unroll
    for (int r = 0; r < 4; r++) mx[r] = fmaxf(mx[r], __shfl_xor(mx[r], o, 64));
  float sum[4] = {0.f, 0.f, 0.f, 0.f};
#pragma unroll
  for (int n = 0; n < 9; n++)
#pragma unroll
    for (int r = 0; r < 4; r++) {
      float p = __expf(sc[n][r] - mx[r]);
      sc[n][r] = p;
      sum[r] += p;
    }
#pragma unroll
  for (int o = 1; o < 16; o <<= 1)
#pragma unroll
    for (int r = 0; r < 4; r++) sum[r] += __shfl_xor(sum[r], o, 64);
  float inv[4];
#pragma unroll
  for (int r = 0; r < 4; r++) inv[r] = 1.0f / sum[r];

#pragma unroll
  for (int n = 0; n < 9; n++)
#pragma unroll
    for (int r = 0; r < 4; r++)
      Ps[wave][(q4 * 4 + r) * PSS + n * 16 + m] = f2bf(sc[n][r] * inv[r]);
  __syncthreads();

  v4f oacc[4] = {};
#pragma unroll
  for (int c = 0; c < 5; c++) {
    v8bf pa = ld8(&Ps[wave][m * PSS + c * 32 + q4 * 8]);
#pragma unroll
    for (int dt = 0; dt < 4; dt++) {
      v8bf vb = ld8(&Vt[(dt * 16 + m) * VTS + wave * 16 + c * 32 + q4 * 8]);
      oacc[dt] = __builtin_amdgcn_mfma_f32_16x16x32_bf16(pa, vb, oacc[dt], 0, 0, 0);
    }
  }
#pragma unroll
  for (int dt = 0; dt < 4; dt++)
#pragma unroll
    for (int r = 0; r < 4; r++)
      Oatt[(b * 2048 + qb + q4 * 4 + r) * 1024 + h * 64 + dt * 16 + m] = f2bf(oacc[dt][r]);

  // band of dense weights, written directly.
  for (int R = 0; R < 16; R++) {
    int iq = qb + R;
    float* rowp = wout + (size_t)((b * 16 + h) * 2048 + iq) * 2048;
    int lo = iq - 127;
    int t0 = R + 1 + lane * 2;
    float p0 = bf2f(Ps[wave][R * PSS + t0]);
    float p1 = bf2f(Ps[wave][R * PSS + t0 + 1]);
    int j0 = lo + lane * 2;
    if (j0 >= 0) rowp[j0] = p0;
    if (j0 + 1 >= 0) rowp[j0 + 1] = p1;
  }
}

// ---------------- fused tail: out-proj GEMM (bx<256) + band-skip zero-writer ----
// R0's proven overlap pattern: 256 gemm blocks dispatched first (1/CU), 4096
// writer blocks (16 rows each, all 65536 rows) backfill residency slots; the
// ~25 us of GEMM hides inside the ~87 us of streaming zero writes.
__global__ __launch_bounds__(256) void k_tail(const unsigned short* __restrict__ Oat,
                                              const unsigned short* __restrict__ WoT,
                                              const float* __restrict__ bo,
                                              float* __restrict__ out,
                                              float* __restrict__ wout) {
  __shared__ __attribute__((aligned(16))) unsigned short As[128 * 32];
  __shared__ __attribute__((aligned(16))) unsigned short Bs[128 * 32];
  int tid = threadIdx.x, wave = tid >> 6, lane = tid & 63;
  int bx = blockIdx.x;

  if (bx >= 256) {
    zero_rows(wout, (bx - 256) * 16, wave, lane);
    return;
  }
  // ---- gemm role: out[4096][1024] = Oat[4096][1024] x WoT^T + bo
  constexpr int K = 1024;
  int n0 = (bx & 7) * 128, m0 = (bx >> 3) * 128;
  int wm = (wave >> 1) * 64, wn = (wave & 1) * 64;
  int m = lane & 15, q4 = lane >> 4;
  int arow = tid >> 2, acol = (tid & 3) * 8;
  v4f acc[4][4] = {};
  const unsigned short* ga0 = Oat + (m0 + arow) * K + acol;
  const unsigned short* ga1 = Oat + (m0 + 64 + arow) * K + acol;
  const unsigned short* gb0 = WoT + (n0 + arow) * K + acol;
  const unsigned short* gb1 = WoT + (n0 + 64 + arow) * K + acol;
  unsigned short* lA0 = As + wave * 512;
  unsigned short* lA1 = As + 2048 + wave * 512;
  unsigned short* lB0 = Bs + wave * 512;
  unsigned short* lB1 = Bs + 2048 + wave * 512;
  for (int kt = 0; kt < K; kt += 32) {
    gl16(ga0 + kt, lA0);
    gl16(ga1 + kt, lA1);
    gl16(gb0 + kt, lB0);
    gl16(gb1 + kt, lB1);
    __syncthreads();
    v8bf af[4], bfv[4];
#pragma unroll
    for (int mt = 0; mt < 4; mt++) af[mt] = ld8(&As[(wm + mt * 16 + m) * 32 + q4 * 8]);
#pragma unroll
    for (int nt = 0; nt < 4; nt++) bfv[nt] = ld8(&Bs[(wn + nt * 16 + m) * 32 + q4 * 8]);
#pragma unroll
    for (int mt = 0; mt < 4; mt++)
#pragma unroll
      for (int nt = 0; nt < 4; nt++)
        acc[mt][nt] = __builtin_amdgcn_mfma_f32_16x16x32_bf16(af[mt], bfv[nt], acc[mt][nt], 0, 0, 0);
    __syncthreads();
  }
#pragma unroll
  for (int mt = 0; mt < 4; mt++)
#pragma unroll
    for (int nt = 0; nt < 4; nt++) {
      int col = n0 + wn + nt * 16 + m;
      float bb = bo[col];
#pragma unroll
      for (int r = 0; r < 4; r++) {
        int row = m0 + wm + mt * 16 + q4 * 4 + r;
        out[row * 1024 + col] = acc[mt][nt][r] + bb;
      }
    }
}

// ---------------- host launch ----------------
extern "C" void kernel_launch(void* const* d_in, const int* in_sizes, int n_in,
                              void* d_out, int out_size, void* d_ws, size_t ws_size,
                              hipStream_t stream) {
  (void)in_sizes; (void)n_in; (void)out_size; (void)ws_size;
  const float* x  = (const float*)d_in[0];
  const float* Wq = (const float*)d_in[1];
  const float* bq = (const float*)d_in[2];
  const float* Wk = (const float*)d_in[3];
  const float* bk = (const float*)d_in[4];
  const float* Wv = (const float*)d_in[5];
  const float* bv = (const float*)d_in[6];
  const float* Wo = (const float*)d_in[7];
  const float* bo = (const float*)d_in[8];

  char* ws = (char*)d_ws;
  unsigned short* xb   = (unsigned short*)(ws);                  //  8,388,608 B
  unsigned short* WT   = (unsigned short*)(ws + 8388608);        //  6,291,456 B  [3072][1024]
  unsigned short* WoT  = (unsigned short*)(ws + 14680064);       //  2,097,152 B  [1024][1024]
  float*          bqkv = (float*)(ws + 16777216);                //     12,288 B
  unsigned short* QK   = (unsigned short*)(ws + 16789504);       // 16,777,216 B  [4096][2048]
  unsigned short* Oat  = (unsigned short*)(ws + 33566720);       //  8,388,608 B  [4096][1024]
  unsigned short* Vtg  = (unsigned short*)(ws + 41955328);       //  8,388,608 B  [2048][2048]

  float* out  = (float*)d_out;          // [2,2048,1024]
  float* wout = out + 4194304;          // [2,16,2048,2048]

  k_prep<<<8204, 256, 0, stream>>>(x, Wq, Wk, Wv, Wo, bq, bk, bv, xb, WT, WoT, bqkv);
  k_gemm1<<<768, 256, 0, stream>>>(xb, WT, bqkv, QK, Vtg);          // pure QKV gemm + Vtg
  k_attn<<<dim3(32, 16, 2), 256, 0, stream>>>(QK, Vtg, Oat, wout);  // attn + band write
  k_tail<<<4352, 256, 0, stream>>>(Oat, WoT, bo, out, wout);        // 256 gemm + 4096 writers
}

// Round 7
// 650.079 us; speedup vs baseline: 1.2725x; 1.0119x over previous
//
#include <hip/hip_runtime.h>
#include <cmath>

typedef __attribute__((ext_vector_type(8))) __bf16 v8bf;
typedef __attribute__((ext_vector_type(4))) float  v4f;

#define DEV static __device__ __forceinline__

DEV unsigned short f2bf(float f) {
  unsigned u = __builtin_bit_cast(unsigned, f);
  unsigned r = u + 0x7fffu + ((u >> 16) & 1u);   // RNE
  return (unsigned short)(r >> 16);
}
DEV float bf2f(unsigned short s) {
  return __builtin_bit_cast(float, ((unsigned)s) << 16);
}
DEV v8bf ld8(const unsigned short* p) { return *(const v8bf*)p; }

// async global->LDS, 16 B per lane; LDS dest = wave-uniform base + lane*16
DEV void gl16(const unsigned short* g, unsigned short* l) {
  __builtin_amdgcn_global_load_lds(
      (const __attribute__((address_space(1))) unsigned int*)g,
      (__attribute__((address_space(3))) unsigned int*)l, 16, 0, 0);
}

// ---------------- fused prep: cvt_x | weight transpose | bias pack ----------------
__global__ __launch_bounds__(256) void k_prep(const float* __restrict__ x,
                                              const float* __restrict__ Wq,
                                              const float* __restrict__ Wk,
                                              const float* __restrict__ Wv,
                                              const float* __restrict__ Wo,
                                              const float* __restrict__ bq,
                                              const float* __restrict__ bk,
                                              const float* __restrict__ bv,
                                              unsigned short* __restrict__ xb,
                                              unsigned short* __restrict__ WT,
                                              unsigned short* __restrict__ WoT,
                                              float* __restrict__ bqkv) {
  __shared__ float t[32][33];
  int bx = blockIdx.x, tid = threadIdx.x;
  if (bx < 4096) {                               // x fp32 -> bf16, 4 elems/thread
    int i = bx * 256 + tid;
    float4 v = ((const float4*)x)[i];
    unsigned lo = (unsigned)f2bf(v.x) | ((unsigned)f2bf(v.y) << 16);
    unsigned hi = (unsigned)f2bf(v.z) | ((unsigned)f2bf(v.w) << 16);
    ((uint2*)xb)[i] = make_uint2(lo, hi);
  } else if (bx < 8192) {                        // W[k][n] -> WT[n][k] bf16
    int rem = bx - 4096;
    int z = rem >> 10, r2 = rem & 1023;
    const float* src = (z == 0) ? Wq : (z == 1) ? Wk : (z == 2) ? Wv : Wo;
    unsigned short* dst = (z < 3) ? WT + z * 1048576 : WoT;
    int n0 = (r2 & 31) * 32, k0 = (r2 >> 5) * 32;
    int tx = tid & 31, ty = tid >> 5;
    for (int r = ty; r < 32; r += 8)
      t[r][tx] = src[(k0 + r) * 1024 + n0 + tx];
    __syncthreads();
    for (int r = ty; r < 32; r += 8)
      dst[(n0 + r) * 1024 + k0 + tx] = f2bf(t[tx][r]);
  } else {                                       // bias concat
    int i = (bx - 8192) * 256 + tid;
    float v = (i < 1024) ? bq[i] : (i < 2048 ? bk[i - 1024] : bv[i - 2048]);
    bqkv[i] = v;
  }
}

// ---------------- QKV GEMM + fused V-transpose (pure) ----------------
// 128x128 tile, BK=32, gl16 staging, 4 waves each 64x64. grid 768.
// Q/K column-tiles (n0<2048) -> QK[4096][2048]; V tiles (n0>=2048) written
// TRANSPOSED straight to Vtg[(b*16+h)*64+d][2048].
__global__ __launch_bounds__(256) void k_gemm1(const unsigned short* __restrict__ A,
                                               const unsigned short* __restrict__ Bt,
                                               const float* __restrict__ bias,
                                               unsigned short* __restrict__ QK,
                                               unsigned short* __restrict__ Vtg) {
  constexpr int K = 1024;
  __shared__ __attribute__((aligned(16))) unsigned short As[128 * 32];
  __shared__ __attribute__((aligned(16))) unsigned short Bs[128 * 32];
  int tid = threadIdx.x;
  int wave = tid >> 6, lane = tid & 63;
  int gid = blockIdx.x;
  int n0 = (gid % 24) * 128, m0 = (gid / 24) * 128;
  int wm = (wave >> 1) * 64, wn = (wave & 1) * 64;
  int m = lane & 15, q4 = lane >> 4;
  int arow = tid >> 2, acol = (tid & 3) * 8;
  v4f acc[4][4] = {};
  const unsigned short* ga0 = A + (m0 + arow) * K + acol;
  const unsigned short* ga1 = A + (m0 + 64 + arow) * K + acol;
  const unsigned short* gb0 = Bt + (n0 + arow) * K + acol;
  const unsigned short* gb1 = Bt + (n0 + 64 + arow) * K + acol;
  unsigned short* lA0 = As + wave * 512;
  unsigned short* lA1 = As + 2048 + wave * 512;
  unsigned short* lB0 = Bs + wave * 512;
  unsigned short* lB1 = Bs + 2048 + wave * 512;

  for (int kt = 0; kt < K; kt += 32) {
    gl16(ga0 + kt, lA0);
    gl16(ga1 + kt, lA1);
    gl16(gb0 + kt, lB0);
    gl16(gb1 + kt, lB1);
    __syncthreads();
    v8bf af[4], bfv[4];
#pragma unroll
    for (int mt = 0; mt < 4; mt++) af[mt] = ld8(&As[(wm + mt * 16 + m) * 32 + q4 * 8]);
#pragma unroll
    for (int nt = 0; nt < 4; nt++) bfv[nt] = ld8(&Bs[(wn + nt * 16 + m) * 32 + q4 * 8]);
#pragma unroll
    for (int mt = 0; mt < 4; mt++)
#pragma unroll
      for (int nt = 0; nt < 4; nt++)
        acc[mt][nt] = __builtin_amdgcn_mfma_f32_16x16x32_bf16(af[mt], bfv[nt], acc[mt][nt], 0, 0, 0);
    __syncthreads();
  }
  if (n0 < 2048) {                               // Q,K -> QK[4096][2048]
#pragma unroll
    for (int mt = 0; mt < 4; mt++)
#pragma unroll
      for (int nt = 0; nt < 4; nt++) {
        int col = n0 + wn + nt * 16 + m;
        float bb = bias[col];
#pragma unroll
        for (int r = 0; r < 4; r++) {
          int row = m0 + wm + mt * 16 + q4 * 4 + r;
          QK[row * 2048 + col] = f2bf(acc[mt][nt][r] + bb);
        }
      }
  } else {                                       // V -> Vtg transposed, 8B/lane
    int b = m0 >> 11;
#pragma unroll
    for (int mt = 0; mt < 4; mt++)
#pragma unroll
      for (int nt = 0; nt < 4; nt++) {
        int d = n0 - 2048 + wn + nt * 16 + m;    // [0,1024)
        int h = d >> 6, dd = d & 63;
        float bb = bias[2048 + d];
        int vrow = (b * 16 + h) * 64 + dd;
        int s0 = (m0 + wm + mt * 16 + q4 * 4) & 2047;
        unsigned short u0 = f2bf(acc[mt][nt][0] + bb);
        unsigned short u1 = f2bf(acc[mt][nt][1] + bb);
        unsigned short u2 = f2bf(acc[mt][nt][2] + bb);
        unsigned short u3 = f2bf(acc[mt][nt][3] + bb);
        unsigned lo = (unsigned)u0 | ((unsigned)u1 << 16);
        unsigned hi = (unsigned)u2 | ((unsigned)u3 << 16);
        *(uint2*)&Vtg[(size_t)vrow * 2048 + s0] = make_uint2(lo, hi);
      }
  }
}

// ---------------- sliding-window attention (no V staging; band -> cb) ----------
// grid dim3(32,16,2): one block = (b, h, 64 queries), 4 waves x 16 q.
// PV B-fragments read DIRECTLY from pre-transposed Vtg (per-block V slice is
// ~26 KB, L2-resident -> staging was pure overhead; LDS 48->21.5 KB doubles
// occupancy). Band P values go to cb for k_tail's full-row writer merge.
__global__ __launch_bounds__(256) void k_attn(const unsigned short* __restrict__ QK,
                                              const unsigned short* __restrict__ Vtg,
                                              unsigned short* __restrict__ Oatt,
                                              unsigned short* __restrict__ cb) {
  constexpr int PSS = 168;
  __shared__ __attribute__((aligned(16))) unsigned short Ps[4][16 * PSS];
  int tid = threadIdx.x, wave = tid >> 6, lane = tid & 63;
  int b = blockIdx.z, h = blockIdx.y, i0 = blockIdx.x * 64;
  int kbase = i0 - 128;
  const int ld = 2048;
  const unsigned short* Qg = QK + (size_t)b * 2048 * ld + h * 64;
  const unsigned short* Kg = Qg + 1024;
  const unsigned short* vsrc = Vtg + (size_t)(b * 16 + h) * 64 * 2048;

  // zero Ps pad cols [144,168) (read by PV c=4 chunk; zero P kills garbage V)
  for (int c = lane; c < 16 * 24; c += 64)
    Ps[wave][(c / 24) * PSS + 144 + (c % 24)] = 0;

  int qb = i0 + wave * 16;
  int m = lane & 15, q4 = lane >> 4;

  const unsigned short* qrow = Qg + (qb + m) * ld;
  v8bf qa0 = ld8(qrow + q4 * 8);
  v8bf qa1 = ld8(qrow + 32 + q4 * 8);

  v4f sc[9];
#pragma unroll
  for (int n = 0; n < 9; n++) {
    int key = kbase + wave * 16 + n * 16 + m;
    int kg = key < 0 ? 0 : key;
    const unsigned short* krow = Kg + kg * ld;
    v8bf kb0 = ld8(krow + q4 * 8);
    v8bf kb1 = ld8(krow + 32 + q4 * 8);
    v4f z = {0.f, 0.f, 0.f, 0.f};
    z = __builtin_amdgcn_mfma_f32_16x16x32_bf16(qa0, kb0, z, 0, 0, 0);
    z = __builtin_amdgcn_mfma_f32_16x16x32_bf16(qa1, kb1, z, 0, 0, 0);
    sc[n] = z;
  }
  float mx[4] = {-3e38f, -3e38f, -3e38f, -3e38f};
#pragma unroll
  for (int n = 0; n < 9; n++)
#pragma unroll
    for (int r = 0; r < 4; r++) {
      int i = qb + q4 * 4 + r;
      int j = kbase + wave * 16 + n * 16 + m;
      float v = sc[n][r] * 0.125f;
      bool ok = (j >= 0) && (j <= i) && (j > i - 128);
      v = ok ? v : -3e38f;
      sc[n][r] = v;
      mx[r] = fmaxf(mx[r], v);
    }
#pragma unroll
  for (int o = 1; o < 16; o <<= 1)
#pragma unroll
    for (int r = 0; r < 4; r++) mx[r] = fmaxf(mx[r], __shfl_xor(mx[r], o, 64));
  float sum[4] = {0.f, 0.f, 0.f, 0.f};
#pragma unroll
  for (int n = 0; n < 9; n++)
#pragma unroll
    for (int r = 0; r < 4; r++) {
      float p = __expf(sc[n][r] - mx[r]);
      sc[n][r] = p;
      sum[r] += p;
    }
#pragma unroll
  for (int o = 1; o < 16; o <<= 1)
#pragma unroll
    for (int r = 0; r < 4; r++) sum[r] += __shfl_xor(sum[r], o, 64);
  float inv[4];
#pragma unroll
  for (int r = 0; r < 4; r++) inv[r] = 1.0f / sum[r];

#pragma unroll
  for (int n = 0; n < 9; n++)
#pragma unroll
    for (int r = 0; r < 4; r++)
      Ps[wave][(q4 * 4 + r) * PSS + n * 16 + m] = f2bf(sc[n][r] * inv[r]);
  __syncthreads();

  v4f oacc[4] = {};
#pragma unroll
  for (int c = 0; c < 5; c++) {
    v8bf pa = ld8(&Ps[wave][m * PSS + c * 32 + q4 * 8]);
    int jc = kbase + wave * 16 + c * 32 + q4 * 8;   // 8-aligned chunk
    if (jc < 0) jc = 0;                              // P=0 masks these keys
    if (jc > 2040) jc = 2040;                        // P pad zeros mask these
#pragma unroll
    for (int dt = 0; dt < 4; dt++) {
      v8bf vb = ld8(vsrc + (size_t)(dt * 16 + m) * 2048 + jc);
      oacc[dt] = __builtin_amdgcn_mfma_f32_16x16x32_bf16(pa, vb, oacc[dt], 0, 0, 0);
    }
  }
#pragma unroll
  for (int dt = 0; dt < 4; dt++)
#pragma unroll
    for (int r = 0; r < 4; r++)
      Oatt[(b * 2048 + qb + q4 * 4 + r) * 1024 + h * 64 + dt * 16 + m] = f2bf(oacc[dt][r]);

  // band values -> cb[row][128] bf16 (t = R+1+2*lane <-> key j = lo+2*lane)
  for (int R = 0; R < 16; R++) {
    int row = (b * 16 + h) * 2048 + qb + R;
    unsigned short p0 = Ps[wave][R * PSS + R + 1 + lane * 2];
    unsigned short p1 = Ps[wave][R * PSS + R + 2 + lane * 2];
    ((unsigned*)cb)[row * 64 + lane] = (unsigned)p0 | ((unsigned)p1 << 16);
  }
}

// ---------------- fused tail: out-proj GEMM (bx<256) + full-row writer ----------
// R0's proven overlap: 256 gemm blocks first (1/CU), 4096 writer blocks backfill
// residency; each writer streams 16 full wout rows with unpredicated v4f nt
// stores, merging the band from cb (no holes, no partial-line RMW).
__global__ __launch_bounds__(256) void k_tail(const unsigned short* __restrict__ Oat,
                                              const unsigned short* __restrict__ WoT,
                                              const float* __restrict__ bo,
                                              float* __restrict__ out,
                                              const unsigned short* __restrict__ cb,
                                              float* __restrict__ wout) {
  __shared__ __attribute__((aligned(16))) unsigned short As[128 * 32];
  __shared__ __attribute__((aligned(16))) unsigned short Bs[128 * 32];
  int tid = threadIdx.x, wave = tid >> 6, lane = tid & 63;

  if (blockIdx.x < 256) {
    // ---- gemm role: out[4096][1024] = Oat[4096][1024] x WoT^T + bo
    constexpr int K = 1024;
    int bx = blockIdx.x;
    int n0 = (bx & 7) * 128, m0 = (bx >> 3) * 128;
    int wm = (wave >> 1) * 64, wn = (wave & 1) * 64;
    int m = lane & 15, q4 = lane >> 4;
    int arow = tid >> 2, acol = (tid & 3) * 8;
    v4f acc[4][4] = {};
    const unsigned short* ga0 = Oat + (m0 + arow) * K + acol;
    const unsigned short* ga1 = Oat + (m0 + 64 + arow) * K + acol;
    const unsigned short* gb0 = WoT + (n0 + arow) * K + acol;
    const unsigned short* gb1 = WoT + (n0 + 64 + arow) * K + acol;
    unsigned short* lA0 = As + wave * 512;
    unsigned short* lA1 = As + 2048 + wave * 512;
    unsigned short* lB0 = Bs + wave * 512;
    unsigned short* lB1 = Bs + 2048 + wave * 512;
    for (int kt = 0; kt < K; kt += 32) {
      gl16(ga0 + kt, lA0);
      gl16(ga1 + kt, lA1);
      gl16(gb0 + kt, lB0);
      gl16(gb1 + kt, lB1);
      __syncthreads();
      v8bf af[4], bfv[4];
#pragma unroll
      for (int mt = 0; mt < 4; mt++) af[mt] = ld8(&As[(wm + mt * 16 + m) * 32 + q4 * 8]);
#pragma unroll
      for (int nt = 0; nt < 4; nt++) bfv[nt] = ld8(&Bs[(wn + nt * 16 + m) * 32 + q4 * 8]);
#pragma unroll
      for (int mt = 0; mt < 4; mt++)
#pragma unroll
        for (int nt = 0; nt < 4; nt++)
          acc[mt][nt] = __builtin_amdgcn_mfma_f32_16x16x32_bf16(af[mt], bfv[nt], acc[mt][nt], 0, 0, 0);
      __syncthreads();
    }
#pragma unroll
    for (int mt = 0; mt < 4; mt++)
#pragma unroll
      for (int nt = 0; nt < 4; nt++) {
        int col = n0 + wn + nt * 16 + m;
        float bb = bo[col];
#pragma unroll
        for (int r = 0; r < 4; r++) {
          int row = m0 + wm + mt * 16 + q4 * 4 + r;
          out[row * 1024 + col] = acc[mt][nt][r] + bb;
        }
      }
  } else {
    // ---- writer role: full dense-weights rows, nontemporal streaming stores
    int wb = blockIdx.x - 256;
    int rbase = wb * 16 + wave * 4;
    for (int rr = 0; rr < 4; rr++) {
      int row = rbase + rr;
      int i = row & 2047;
      float* rowp = wout + (size_t)row * 2048;
      const unsigned short* crow = cb + (size_t)row * 128;
      int lo = i - 127;
#pragma unroll
      for (int it = 0; it < 8; it++) {
        int col = it * 256 + lane * 4;
        v4f v = {0.f, 0.f, 0.f, 0.f};
        if (col <= i && col + 3 >= lo) {
#pragma unroll
          for (int e = 0; e < 4; e++) {
            int j = col + e;
            if (j >= lo && j <= i && j >= 0)
              v[e] = bf2f(crow[j - lo]);
          }
        }
        __builtin_nontemporal_store(v, (v4f*)(rowp + col));
      }
    }
  }
}

// ---------------- host launch ----------------
extern "C" void kernel_launch(void* const* d_in, const int* in_sizes, int n_in,
                              void* d_out, int out_size, void* d_ws, size_t ws_size,
                              hipStream_t stream) {
  (void)in_sizes; (void)n_in; (void)out_size; (void)ws_size;
  const float* x  = (const float*)d_in[0];
  const float* Wq = (const float*)d_in[1];
  const float* bq = (const float*)d_in[2];
  const float* Wk = (const float*)d_in[3];
  const float* bk = (const float*)d_in[4];
  const float* Wv = (const float*)d_in[5];
  const float* bv = (const float*)d_in[6];
  const float* Wo = (const float*)d_in[7];
  const float* bo = (const float*)d_in[8];

  char* ws = (char*)d_ws;
  unsigned short* xb   = (unsigned short*)(ws);                  //  8,388,608 B
  unsigned short* WT   = (unsigned short*)(ws + 8388608);        //  6,291,456 B  [3072][1024]
  unsigned short* WoT  = (unsigned short*)(ws + 14680064);       //  2,097,152 B  [1024][1024]
  float*          bqkv = (float*)(ws + 16777216);                //     12,288 B
  unsigned short* QK   = (unsigned short*)(ws + 16789504);       // 16,777,216 B  [4096][2048]
  unsigned short* Oat  = (unsigned short*)(ws + 33566720);       //  8,388,608 B  [4096][1024]
  unsigned short* Vtg  = (unsigned short*)(ws + 41955328);       //  8,388,608 B  [2048][2048]
  unsigned short* cb   = (unsigned short*)(ws + 50343936);       // 16,777,216 B  [65536][128]

  float* out  = (float*)d_out;          // [2,2048,1024]
  float* wout = out + 4194304;          // [2,16,2048,2048]

  k_prep<<<8204, 256, 0, stream>>>(x, Wq, Wk, Wv, Wo, bq, bk, bv, xb, WT, WoT, bqkv);
  k_gemm1<<<768, 256, 0, stream>>>(xb, WT, bqkv, QK, Vtg);          // QKV gemm + fused Vtg
  k_attn<<<dim3(32, 16, 2), 256, 0, stream>>>(QK, Vtg, Oat, cb);    // attn, no V staging
  k_tail<<<4352, 256, 0, stream>>>(Oat, WoT, bo, out, cb, wout);    // 256 gemm + 4096 writers
}

// Round 8
// 646.757 us; speedup vs baseline: 1.2790x; 1.0051x over previous
//
#include <hip/hip_runtime.h>
#include <cmath>

typedef __attribute__((ext_vector_type(8))) __bf16 v8bf;
typedef __attribute__((ext_vector_type(4))) float  v4f;

#define DEV static __device__ __forceinline__

DEV unsigned short f2bf(float f) {
  unsigned u = __builtin_bit_cast(unsigned, f);
  unsigned r = u + 0x7fffu + ((u >> 16) & 1u);   // RNE
  return (unsigned short)(r >> 16);
}
DEV float bf2f(unsigned short s) {
  return __builtin_bit_cast(float, ((unsigned)s) << 16);
}
DEV v8bf ld8(const unsigned short* p) { return *(const v8bf*)p; }

// async global->LDS, 16 B per lane; LDS dest = wave-uniform base + lane*16
DEV void gl16(const unsigned short* g, unsigned short* l) {
  __builtin_amdgcn_global_load_lds(
      (const __attribute__((address_space(1))) unsigned int*)g,
      (__attribute__((address_space(3))) unsigned int*)l, 16, 0, 0);
}

// ---------------- fused prep: cvt_x | weight transpose | bias pack ----------------
__global__ __launch_bounds__(256) void k_prep(const float* __restrict__ x,
                                              const float* __restrict__ Wq,
                                              const float* __restrict__ Wk,
                                              const float* __restrict__ Wv,
                                              const float* __restrict__ Wo,
                                              const float* __restrict__ bq,
                                              const float* __restrict__ bk,
                                              const float* __restrict__ bv,
                                              unsigned short* __restrict__ xb,
                                              unsigned short* __restrict__ WT,
                                              unsigned short* __restrict__ WoT,
                                              float* __restrict__ bqkv) {
  __shared__ float t[32][33];
  int bx = blockIdx.x, tid = threadIdx.x;
  if (bx < 4096) {                               // x fp32 -> bf16, 4 elems/thread
    int i = bx * 256 + tid;
    float4 v = ((const float4*)x)[i];
    unsigned lo = (unsigned)f2bf(v.x) | ((unsigned)f2bf(v.y) << 16);
    unsigned hi = (unsigned)f2bf(v.z) | ((unsigned)f2bf(v.w) << 16);
    ((uint2*)xb)[i] = make_uint2(lo, hi);
  } else if (bx < 8192) {                        // W[k][n] -> WT[n][k] bf16
    int rem = bx - 4096;
    int z = rem >> 10, r2 = rem & 1023;
    const float* src = (z == 0) ? Wq : (z == 1) ? Wk : (z == 2) ? Wv : Wo;
    unsigned short* dst = (z < 3) ? WT + z * 1048576 : WoT;
    int n0 = (r2 & 31) * 32, k0 = (r2 >> 5) * 32;
    int tx = tid & 31, ty = tid >> 5;
    for (int r = ty; r < 32; r += 8)
      t[r][tx] = src[(k0 + r) * 1024 + n0 + tx];
    __syncthreads();
    for (int r = ty; r < 32; r += 8)
      dst[(n0 + r) * 1024 + k0 + tx] = f2bf(t[tx][r]);
  } else {                                       // bias concat
    int i = (bx - 8192) * 256 + tid;
    float v = (i < 1024) ? bq[i] : (i < 2048 ? bk[i - 1024] : bv[i - 2048]);
    bqkv[i] = v;
  }
}

// ---------------- QKV GEMM + fused V-transpose, coalesced LDS-staged epilogue ----
// 128x128 tile, BK=32, gl16 staging, 4 waves each 64x64. grid 768.
// Epilogue v2: each wave stages its 64x64 C-tile in a wave-private LDS region
// (stride 68 u16 to spread banks), then streams 128-B-contiguous dwordx2 rows:
//   Q/K tiles row-major -> QK[4096][2048];
//   V tiles staged TRANSPOSED -> Vtg[(b*16+h)*64+d][2048] rows contiguous.
// Replaces 64 scalar 2-B stores (Q/K) and 16 scattered 8-B stores (V) per
// thread with 16 coalesced 8-B stores -> no sector write amplification.
__global__ __launch_bounds__(256) void k_gemm1(const unsigned short* __restrict__ A,
                                               const unsigned short* __restrict__ Bt,
                                               const float* __restrict__ bias,
                                               unsigned short* __restrict__ QK,
                                               unsigned short* __restrict__ Vtg) {
  constexpr int K = 1024;
  // 17408 shorts = 34.8 KB: K-loop uses [0,8192) as As|Bs; epilogue reuses all
  // of it as 4 wave-private 64x68 staging tiles (4352 shorts each).
  __shared__ __attribute__((aligned(16))) unsigned short SM[17408];
  unsigned short* As = SM;
  unsigned short* Bs = SM + 4096;
  int tid = threadIdx.x;
  int wave = tid >> 6, lane = tid & 63;
  int gid = blockIdx.x;
  int n0 = (gid % 24) * 128, m0 = (gid / 24) * 128;
  int wm = (wave >> 1) * 64, wn = (wave & 1) * 64;
  int m = lane & 15, q4 = lane >> 4;
  int arow = tid >> 2, acol = (tid & 3) * 8;
  v4f acc[4][4] = {};
  const unsigned short* ga0 = A + (m0 + arow) * K + acol;
  const unsigned short* ga1 = A + (m0 + 64 + arow) * K + acol;
  const unsigned short* gb0 = Bt + (n0 + arow) * K + acol;
  const unsigned short* gb1 = Bt + (n0 + 64 + arow) * K + acol;
  unsigned short* lA0 = As + wave * 512;
  unsigned short* lA1 = As + 2048 + wave * 512;
  unsigned short* lB0 = Bs + wave * 512;
  unsigned short* lB1 = Bs + 2048 + wave * 512;

  for (int kt = 0; kt < K; kt += 32) {
    gl16(ga0 + kt, lA0);
    gl16(ga1 + kt, lA1);
    gl16(gb0 + kt, lB0);
    gl16(gb1 + kt, lB1);
    __syncthreads();
    v8bf af[4], bfv[4];
#pragma unroll
    for (int mt = 0; mt < 4; mt++) af[mt] = ld8(&As[(wm + mt * 16 + m) * 32 + q4 * 8]);
#pragma unroll
    for (int nt = 0; nt < 4; nt++) bfv[nt] = ld8(&Bs[(wn + nt * 16 + m) * 32 + q4 * 8]);
#pragma unroll
    for (int mt = 0; mt < 4; mt++)
#pragma unroll
      for (int nt = 0; nt < 4; nt++)
        acc[mt][nt] = __builtin_amdgcn_mfma_f32_16x16x32_bf16(af[mt], bfv[nt], acc[mt][nt], 0, 0, 0);
    __syncthreads();
  }

  // ---- epilogue (after final barrier; wave-private LDS regions, no cross-wave dep)
  unsigned short* W = SM + wave * 4352;        // 64 x 68 u16
  if (n0 < 2048) {                             // Q,K -> QK[4096][2048], row-major
#pragma unroll
    for (int mt = 0; mt < 4; mt++)
#pragma unroll
      for (int nt = 0; nt < 4; nt++) {
        float bb = bias[n0 + wn + nt * 16 + m];
#pragma unroll
        for (int r = 0; r < 4; r++)
          W[(mt * 16 + q4 * 4 + r) * 68 + nt * 16 + m] = f2bf(acc[mt][nt][r] + bb);
      }
#pragma unroll
    for (int op = 0; op < 16; op++) {
      int lr = op * 4 + (lane >> 4), lc = (lane & 15) * 4;
      uint2 v = *(const uint2*)&W[lr * 68 + lc];
      *(uint2*)&QK[(size_t)(m0 + wm + lr) * 2048 + n0 + wn + lc] = v;
    }
  } else {                                     // V -> Vtg, staged transposed
    int b = m0 >> 11;
    int d0 = n0 - 2048 + wn;                   // 64-aligned: whole wave = one head
    int h = d0 >> 6;
#pragma unroll
    for (int mt = 0; mt < 4; mt++)
#pragma unroll
      for (int nt = 0; nt < 4; nt++) {
        float bb = bias[2048 + d0 + nt * 16 + m];
#pragma unroll
        for (int rr = 0; rr < 2; rr++) {
          unsigned p = (unsigned)f2bf(acc[mt][nt][2 * rr] + bb)
                     | ((unsigned)f2bf(acc[mt][nt][2 * rr + 1] + bb) << 16);
          *(unsigned*)&W[(nt * 16 + m) * 68 + mt * 16 + q4 * 4 + rr * 2] = p;
        }
      }
    int vbase = (b * 16 + h) * 64;
    int s0 = (m0 + wm) & 2047;
#pragma unroll
    for (int op = 0; op < 16; op++) {
      int ld = op * 4 + (lane >> 4), ls = (lane & 15) * 4;
      uint2 v = *(const uint2*)&W[ld * 68 + ls];
      *(uint2*)&Vtg[(size_t)(vbase + ld) * 2048 + s0 + ls] = v;
    }
  }
}

// ---------------- sliding-window attention (no V staging; band -> cb) ----------
// grid dim3(32,16,2): one block = (b, h, 64 queries), 4 waves x 16 q.
// PV B-fragments read DIRECTLY from pre-transposed Vtg (per-block V slice is
// ~26 KB, L2-resident). Band P values go to cb for k_tail's writer merge.
__global__ __launch_bounds__(256) void k_attn(const unsigned short* __restrict__ QK,
                                              const unsigned short* __restrict__ Vtg,
                                              unsigned short* __restrict__ Oatt,
                                              unsigned short* __restrict__ cb) {
  constexpr int PSS = 168;
  __shared__ __attribute__((aligned(16))) unsigned short Ps[4][16 * PSS];
  int tid = threadIdx.x, wave = tid >> 6, lane = tid & 63;
  int b = blockIdx.z, h = blockIdx.y, i0 = blockIdx.x * 64;
  int kbase = i0 - 128;
  const int ld = 2048;
  const unsigned short* Qg = QK + (size_t)b * 2048 * ld + h * 64;
  const unsigned short* Kg = Qg + 1024;
  const unsigned short* vsrc = Vtg + (size_t)(b * 16 + h) * 64 * 2048;

  // zero Ps pad cols [144,168) (read by PV c=4 chunk; zero P kills garbage V)
  for (int c = lane; c < 16 * 24; c += 64)
    Ps[wave][(c / 24) * PSS + 144 + (c % 24)] = 0;

  int qb = i0 + wave * 16;
  int m = lane & 15, q4 = lane >> 4;

  const unsigned short* qrow = Qg + (qb + m) * ld;
  v8bf qa0 = ld8(qrow + q4 * 8);
  v8bf qa1 = ld8(qrow + 32 + q4 * 8);

  v4f sc[9];
#pragma unroll
  for (int n = 0; n < 9; n++) {
    int key = kbase + wave * 16 + n * 16 + m;
    int kg = key < 0 ? 0 : key;
    const unsigned short* krow = Kg + kg * ld;
    v8bf kb0 = ld8(krow + q4 * 8);
    v8bf kb1 = ld8(krow + 32 + q4 * 8);
    v4f z = {0.f, 0.f, 0.f, 0.f};
    z = __builtin_amdgcn_mfma_f32_16x16x32_bf16(qa0, kb0, z, 0, 0, 0);
    z = __builtin_amdgcn_mfma_f32_16x16x32_bf16(qa1, kb1, z, 0, 0, 0);
    sc[n] = z;
  }
  float mx[4] = {-3e38f, -3e38f, -3e38f, -3e38f};
#pragma unroll
  for (int n = 0; n < 9; n++)
#pragma unroll
    for (int r = 0; r < 4; r++) {
      int i = qb + q4 * 4 + r;
      int j = kbase + wave * 16 + n * 16 + m;
      float v = sc[n][r] * 0.125f;
      bool ok = (j >= 0) && (j <= i) && (j > i - 128);
      v = ok ? v : -3e38f;
      sc[n][r] = v;
      mx[r] = fmaxf(mx[r], v);
    }
#pragma unroll
  for (int o = 1; o < 16; o <<= 1)
#pragma unroll
    for (int r = 0; r < 4; r++) mx[r] = fmaxf(mx[r], __shfl_xor(mx[r], o, 64));
  float sum[4] = {0.f, 0.f, 0.f, 0.f};
#pragma unroll
  for (int n = 0; n < 9; n++)
#pragma unroll
    for (int r = 0; r < 4; r++) {
      float p = __expf(sc[n][r] - mx[r]);
      sc[n][r] = p;
      sum[r] += p;
    }
#pragma unroll
  for (int o = 1; o < 16; o <<= 1)
#pragma unroll
    for (int r = 0; r < 4; r++) sum[r] += __shfl_xor(sum[r], o, 64);
  float inv[4];
#pragma unroll
  for (int r = 0; r < 4; r++) inv[r] = 1.0f / sum[r];

#pragma unroll
  for (int n = 0; n < 9; n++)
#pragma unroll
    for (int r = 0; r < 4; r++)
      Ps[wave][(q4 * 4 + r) * PSS + n * 16 + m] = f2bf(sc[n][r] * inv[r]);
  __syncthreads();

  v4f oacc[4] = {};
#pragma unroll
  for (int c = 0; c < 5; c++) {
    v8bf pa = ld8(&Ps[wave][m * PSS + c * 32 + q4 * 8]);
    int jc = kbase + wave * 16 + c * 32 + q4 * 8;   // 8-aligned chunk
    if (jc < 0) jc = 0;                              // P=0 masks these keys
    if (jc > 2040) jc = 2040;                        // P pad zeros mask these
#pragma unroll
    for (int dt = 0; dt < 4; dt++) {
      v8bf vb = ld8(vsrc + (size_t)(dt * 16 + m) * 2048 + jc);
      oacc[dt] = __builtin_amdgcn_mfma_f32_16x16x32_bf16(pa, vb, oacc[dt], 0, 0, 0);
    }
  }
#pragma unroll
  for (int dt = 0; dt < 4; dt++)
#pragma unroll
    for (int r = 0; r < 4; r++)
      Oatt[(b * 2048 + qb + q4 * 4 + r) * 1024 + h * 64 + dt * 16 + m] = f2bf(oacc[dt][r]);

  // band values -> cb[row][128] bf16 (t = R+1+2*lane <-> key j = lo+2*lane)
  for (int R = 0; R < 16; R++) {
    int row = (b * 16 + h) * 2048 + qb + R;
    unsigned short p0 = Ps[wave][R * PSS + R + 1 + lane * 2];
    unsigned short p1 = Ps[wave][R * PSS + R + 2 + lane * 2];
    ((unsigned*)cb)[row * 64 + lane] = (unsigned)p0 | ((unsigned)p1 << 16);
  }
}

// ---------------- fused tail: out-proj GEMM (bx<256) + full-row writer ----------
// R0's proven overlap: 256 gemm blocks first (1/CU), 4096 writer blocks backfill
// residency; each writer streams 16 full wout rows with unpredicated v4f nt
// stores, merging the band from cb (no holes, no partial-line RMW).
__global__ __launch_bounds__(256) void k_tail(const unsigned short* __restrict__ Oat,
                                              const unsigned short* __restrict__ WoT,
                                              const float* __restrict__ bo,
                                              float* __restrict__ out,
                                              const unsigned short* __restrict__ cb,
                                              float* __restrict__ wout) {
  __shared__ __attribute__((aligned(16))) unsigned short As[128 * 32];
  __shared__ __attribute__((aligned(16))) unsigned short Bs[128 * 32];
  int tid = threadIdx.x, wave = tid >> 6, lane = tid & 63;

  if (blockIdx.x < 256) {
    // ---- gemm role: out[4096][1024] = Oat[4096][1024] x WoT^T + bo
    constexpr int K = 1024;
    int bx = blockIdx.x;
    int n0 = (bx & 7) * 128, m0 = (bx >> 3) * 128;
    int wm = (wave >> 1) * 64, wn = (wave & 1) * 64;
    int m = lane & 15, q4 = lane >> 4;
    int arow = tid >> 2, acol = (tid & 3) * 8;
    v4f acc[4][4] = {};
    const unsigned short* ga0 = Oat + (m0 + arow) * K + acol;
    const unsigned short* ga1 = Oat + (m0 + 64 + arow) * K + acol;
    const unsigned short* gb0 = WoT + (n0 + arow) * K + acol;
    const unsigned short* gb1 = WoT + (n0 + 64 + arow) * K + acol;
    unsigned short* lA0 = As + wave * 512;
    unsigned short* lA1 = As + 2048 + wave * 512;
    unsigned short* lB0 = Bs + wave * 512;
    unsigned short* lB1 = Bs + 2048 + wave * 512;
    for (int kt = 0; kt < K; kt += 32) {
      gl16(ga0 + kt, lA0);
      gl16(ga1 + kt, lA1);
      gl16(gb0 + kt, lB0);
      gl16(gb1 + kt, lB1);
      __syncthreads();
      v8bf af[4], bfv[4];
#pragma unroll
      for (int mt = 0; mt < 4; mt++) af[mt] = ld8(&As[(wm + mt * 16 + m) * 32 + q4 * 8]);
#pragma unroll
      for (int nt = 0; nt < 4; nt++) bfv[nt] = ld8(&Bs[(wn + nt * 16 + m) * 32 + q4 * 8]);
#pragma unroll
      for (int mt = 0; mt < 4; mt++)
#pragma unroll
        for (int nt = 0; nt < 4; nt++)
          acc[mt][nt] = __builtin_amdgcn_mfma_f32_16x16x32_bf16(af[mt], bfv[nt], acc[mt][nt], 0, 0, 0);
      __syncthreads();
    }
#pragma unroll
    for (int mt = 0; mt < 4; mt++)
#pragma unroll
      for (int nt = 0; nt < 4; nt++) {
        int col = n0 + wn + nt * 16 + m;
        float bb = bo[col];
#pragma unroll
        for (int r = 0; r < 4; r++) {
          int row = m0 + wm + mt * 16 + q4 * 4 + r;
          out[row * 1024 + col] = acc[mt][nt][r] + bb;
        }
      }
  } else {
    // ---- writer role: full dense-weights rows, nontemporal streaming stores
    int wb = blockIdx.x - 256;
    int rbase = wb * 16 + wave * 4;
    for (int rr = 0; rr < 4; rr++) {
      int row = rbase + rr;
      int i = row & 2047;
      float* rowp = wout + (size_t)row * 2048;
      const unsigned short* crow = cb + (size_t)row * 128;
      int lo = i - 127;
#pragma unroll
      for (int it = 0; it < 8; it++) {
        int col = it * 256 + lane * 4;
        v4f v = {0.f, 0.f, 0.f, 0.f};
        if (col <= i && col + 3 >= lo) {
#pragma unroll
          for (int e = 0; e < 4; e++) {
            int j = col + e;
            if (j >= lo && j <= i && j >= 0)
              v[e] = bf2f(crow[j - lo]);
          }
        }
        __builtin_nontemporal_store(v, (v4f*)(rowp + col));
      }
    }
  }
}

// ---------------- host launch ----------------
extern "C" void kernel_launch(void* const* d_in, const int* in_sizes, int n_in,
                              void* d_out, int out_size, void* d_ws, size_t ws_size,
                              hipStream_t stream) {
  (void)in_sizes; (void)n_in; (void)out_size; (void)ws_size;
  const float* x  = (const float*)d_in[0];
  const float* Wq = (const float*)d_in[1];
  const float* bq = (const float*)d_in[2];
  const float* Wk = (const float*)d_in[3];
  const float* bk = (const float*)d_in[4];
  const float* Wv = (const float*)d_in[5];
  const float* bv = (const float*)d_in[6];
  const float* Wo = (const float*)d_in[7];
  const float* bo = (const float*)d_in[8];

  char* ws = (char*)d_ws;
  unsigned short* xb   = (unsigned short*)(ws);                  //  8,388,608 B
  unsigned short* WT   = (unsigned short*)(ws + 8388608);        //  6,291,456 B  [3072][1024]
  unsigned short* WoT  = (unsigned short*)(ws + 14680064);       //  2,097,152 B  [1024][1024]
  float*          bqkv = (float*)(ws + 16777216);                //     12,288 B
  unsigned short* QK   = (unsigned short*)(ws + 16789504);       // 16,777,216 B  [4096][2048]
  unsigned short* Oat  = (unsigned short*)(ws + 33566720);       //  8,388,608 B  [4096][1024]
  unsigned short* Vtg  = (unsigned short*)(ws + 41955328);       //  8,388,608 B  [2048][2048]
  unsigned short* cb   = (unsigned short*)(ws + 50343936);       // 16,777,216 B  [65536][128]

  float* out  = (float*)d_out;          // [2,2048,1024]
  float* wout = out + 4194304;          // [2,16,2048,2048]

  k_prep<<<8204, 256, 0, stream>>>(x, Wq, Wk, Wv, Wo, bq, bk, bv, xb, WT, WoT, bqkv);
  k_gemm1<<<768, 256, 0, stream>>>(xb, WT, bqkv, QK, Vtg);          // QKV gemm + coalesced epi
  k_attn<<<dim3(32, 16, 2), 256, 0, stream>>>(QK, Vtg, Oat, cb);    // attn, no V staging
  k_tail<<<4352, 256, 0, stream>>>(Oat, WoT, bo, out, cb, wout);    // 256 gemm + 4096 writers
}